// Round 7
// baseline (148.708 us; speedup 1.0000x reference)
//
#include <hip/hip_runtime.h>
#include <hip/hip_bf16.h>

#define DIM   512
#define NHEAD 8
#define DM    64
#define DL    128
#define BBAG  8
#define NINST 4096
#define MTOT  (BBAG*NINST)     // 32768 instances
#define NCOL  (NHEAD*DM + DL)  // 640 fused output columns (8*64 mh + 128 gate)
#define NCHUNK 8               // pool n-chunks per (h,b)

typedef short   bf16x8 __attribute__((ext_vector_type(8)));
typedef __bf16  bf16v8 __attribute__((ext_vector_type(8)));
typedef float   f32x4  __attribute__((ext_vector_type(4)));
typedef short   s16x4  __attribute__((ext_vector_type(4)));

__device__ __forceinline__ short f2b(float f) {
  __hip_bfloat16 h = __float2bfloat16(f);
  return __builtin_bit_cast(short, h);
}
__device__ __forceinline__ float b2f(short s) {
  __hip_bfloat16 h = __builtin_bit_cast(__hip_bfloat16, s);
  return __bfloat162float(h);
}
__device__ __forceinline__ f32x4 mfma_bf16(bf16x8 a, bf16x8 b, f32x4 c) {
  return __builtin_amdgcn_mfma_f32_16x16x32_bf16(
      __builtin_bit_cast(bf16v8, a), __builtin_bit_cast(bf16v8, b), c, 0, 0, 0);
}

// ---------------------------------------------------------------------------
// Kernel 1: build bf16 weights (slab-major, pre-swizzled; see R2 notes).
// Wt2 shorts[ks*20480 + col*32 + q2*8], q2 = (q + ((col&15)>>1)) & 3.
// Vt[l][m] = V[m][l]
// ---------------------------------------------------------------------------
__global__ void prep_weights(const float* __restrict__ WX, const float* __restrict__ V,
                             const float* __restrict__ gate_w,
                             short* __restrict__ Wt2, short* __restrict__ Vt) {
  int g = blockIdx.x * blockDim.x + threadIdx.x;
  if (g < 16 * 640 * 4) {               // 40960 16-byte pieces of Wt2
    int ks = g / 2560;
    int rem = g - ks * 2560;
    int col = rem >> 2, q = rem & 3;
    int q2 = (q + ((col & 15) >> 1)) & 3;
    short* dst = Wt2 + ks * 20480 + col * 32 + q2 * 8;
    #pragma unroll
    for (int j = 0; j < 8; ++j) {
      int k = ks * 32 + q * 8 + j;
      float v;
      if (col < NHEAD * DM) v = WX[((size_t)(col >> 6) * DIM + k) * DM + (col & 63)];
      else                  v = gate_w[(size_t)k * DL + (col - NHEAD * DM)];
      dst[j] = f2b(v);
    }
  } else {
    int i = g - 16 * 640 * 4;
    if (i < DL * DM) {
      int l = i >> 6, m = i & 63;
      Vt[(size_t)l * DM + m] = f2b(V[(size_t)m * DL + l]);
    }
  }
}

// ---------------------------------------------------------------------------
// Kernel 2: fused projection GEMM  C[32768 x 640] = x[32768 x 512] * Wcat
// BARRIER-FREE: wave w stages AND reads only its own 5 LDS units -> no
// __syncthreads in the K-loop at all; per-wave s_waitcnt vmcnt(0) at iter
// top (prefetch had a full iteration to land). A loaded global->reg (f32)
// and converted in-reg. LDS = 2 x 40 KB B dbuf -> 2 blocks/CU, 1 round.
// ---------------------------------------------------------------------------
__global__ __launch_bounds__(512) void proj_kernel(
    const float* __restrict__ x, const short* __restrict__ Wt2,
    short* __restrict__ mh, short* __restrict__ gate) {
  __shared__ alignas(1024) short lds_b[2][20480];  // 2 x 40 KB B slabs (swizzled)
  const int tid = threadIdx.x;
  const int bm0 = blockIdx.x * 64;
  const int lane = tid & 63;
  const int w = tid >> 6;            // wave 0..7 -> cols [80w, 80w+80)
  const int r = lane & 15;
  const int q = lane >> 4;           // 0..3
  const int swz = ((q + (r >> 1)) & 3) * 16;  // bank-quad swizzle byte offset
  char* ldb = reinterpret_cast<char*>(lds_b);

  // ---- prologue: stage B slab ks=0 into buf 0 (own units only) ----
  #pragma unroll
  for (int i = 0; i < 5; ++i) {
    const int unit = w * 5 + i;
    const short* gsrc = Wt2 + unit * 512 + lane * 8;
    __builtin_amdgcn_global_load_lds(
        (const __attribute__((address_space(1))) void*)gsrc,
        (__attribute__((address_space(3))) void*)(ldb + unit * 1024),
        16, 0, 0);
  }

  f32x4 acc[4][5];
  #pragma unroll
  for (int rt = 0; rt < 4; ++rt)
    #pragma unroll
    for (int ct = 0; ct < 5; ++ct) acc[rt][ct] = f32x4{0.f, 0.f, 0.f, 0.f};

  for (int ks = 0; ks < 16; ++ks) {
    const int cur = ks & 1;
    // B[ks] has been in flight for a full iteration; drain this wave's queue.
    asm volatile("s_waitcnt vmcnt(0)" ::: "memory");
    // --- B-frag reads from own units (conflict-free, swizzled) ---
    bf16x8 bf[5];
    #pragma unroll
    for (int ct = 0; ct < 5; ++ct)
      bf[ct] = *reinterpret_cast<const bf16x8*>(
          ldb + cur * 40960 + (80 * w + 16 * ct + r) * 64 + swz);
    // --- A[ks]: direct global->reg f32 (issued now, consumed after cvt) ---
    f32x4 a0[4], a1[4];
    #pragma unroll
    for (int rt = 0; rt < 4; ++rt) {
      const float* p = x + ((size_t)(bm0 + 16 * rt + r) << 9) + ks * 32 + q * 8;
      a0[rt] = *reinterpret_cast<const f32x4*>(p);
      a1[rt] = *reinterpret_cast<const f32x4*>(p + 4);
    }
    __builtin_amdgcn_sched_barrier(0);   // keep A-loads issued before B-prefetch
    // --- prefetch B[ks+1] into other buffer (own units) ---
    if (ks < 15) {
      #pragma unroll
      for (int i = 0; i < 5; ++i) {
        const int unit = w * 5 + i;
        const short* gsrc = Wt2 + (ks + 1) * 20480 + unit * 512 + lane * 8;
        __builtin_amdgcn_global_load_lds(
            (const __attribute__((address_space(1))) void*)gsrc,
            (__attribute__((address_space(3))) void*)(ldb + (cur ^ 1) * 40960 + unit * 1024),
            16, 0, 0);
      }
    }
    // --- cvt A to bf16 and 20 MFMA (A waits retire before B[ks+1]) ---
    #pragma unroll
    for (int rt = 0; rt < 4; ++rt) {
      bf16x8 af;
      af[0] = f2b(a0[rt][0]); af[1] = f2b(a0[rt][1]);
      af[2] = f2b(a0[rt][2]); af[3] = f2b(a0[rt][3]);
      af[4] = f2b(a1[rt][0]); af[5] = f2b(a1[rt][1]);
      af[6] = f2b(a1[rt][2]); af[7] = f2b(a1[rt][3]);
      #pragma unroll
      for (int ct = 0; ct < 5; ++ct)
        acc[rt][ct] = mfma_bf16(af, bf[ct], acc[rt][ct]);
    }
  }

  // epilogue: D-frag lane mapping row = 4q+j (+16rt), col = r (+16ct)
  #pragma unroll
  for (int rt = 0; rt < 4; ++rt) {
    #pragma unroll
    for (int ct = 0; ct < 5; ++ct) {
      int col = 80 * w + 16 * ct + r;
      #pragma unroll
      for (int j = 0; j < 4; ++j) {
        int grow = bm0 + 16 * rt + 4 * q + j;
        float v = acc[rt][ct][j];
        if (col < NHEAD * DM) {
          mh[((size_t)(col >> 6) * MTOT + grow) * DM + (col & 63)] = f2b(v);
        } else {
          gate[(size_t)grow * DL + (col - NHEAD * DM)] = f2b(1.0f / (1.0f + expf(-v)));
        }
      }
    }
  }
}

// ---------------------------------------------------------------------------
// Kernel 3: scores[h][row] = sum_l tanh( (mh_h . V)[row][l] ) * gate[row][l] * W[h][l]
// ---------------------------------------------------------------------------
__global__ __launch_bounds__(256) void score_kernel(
    const short* __restrict__ mh, const short* __restrict__ gate,
    const short* __restrict__ Vt, const float* __restrict__ W,
    float* __restrict__ scores) {
  const int tid = threadIdx.x;
  const int lane = tid & 63;
  const int wv = tid >> 6;         // 0..3
  const int r = lane & 15, q = lane >> 4;
  const int row0 = blockIdx.x * 64;

  #pragma unroll
  for (int hh = 0; hh < 2; ++hh) {
    const int h = wv * 2 + hh;
    float wc[8];
    #pragma unroll
    for (int ct = 0; ct < 8; ++ct) wc[ct] = W[(size_t)h * DL + 16 * ct + r];

    #pragma unroll
    for (int rt = 0; rt < 4; ++rt) {
      const short* ap = mh + ((size_t)h * MTOT + row0 + 16 * rt + r) * DM + q * 8;
      bf16x8 a0 = *reinterpret_cast<const bf16x8*>(ap);
      bf16x8 a1 = *reinterpret_cast<const bf16x8*>(ap + 32);
      float sc[4] = {0.f, 0.f, 0.f, 0.f};
      #pragma unroll
      for (int ct = 0; ct < 8; ++ct) {
        const short* bp = Vt + (size_t)(16 * ct + r) * DM + q * 8;
        bf16x8 b0 = *reinterpret_cast<const bf16x8*>(bp);
        bf16x8 b1 = *reinterpret_cast<const bf16x8*>(bp + 32);
        f32x4 t = f32x4{0.f, 0.f, 0.f, 0.f};
        t = mfma_bf16(a0, b0, t);
        t = mfma_bf16(a1, b1, t);
        #pragma unroll
        for (int j = 0; j < 4; ++j) {
          int row = row0 + 16 * rt + 4 * q + j;
          int coll = 16 * ct + r;
          float g = b2f(gate[(size_t)row * DL + coll]);
          float d = tanhf(t[j]) * g;
          sc[j] += d * wc[ct];
        }
      }
      #pragma unroll
      for (int j = 0; j < 4; ++j) {
        sc[j] += __shfl_xor(sc[j], 1);
        sc[j] += __shfl_xor(sc[j], 2);
        sc[j] += __shfl_xor(sc[j], 4);
        sc[j] += __shfl_xor(sc[j], 8);
      }
      if (r < 4) {
        float v = (r == 0) ? sc[0] : (r == 1) ? sc[1] : (r == 2) ? sc[2] : sc[3];
        scores[(size_t)h * MTOT + row0 + 16 * rt + 4 * q + r] = v;
      }
    }
  }
}

// ---------------------------------------------------------------------------
// Kernel 4: masked softmax over N per (h,b). soft=0 for n >= true_num[b].
// ---------------------------------------------------------------------------
__global__ __launch_bounds__(256) void softmax_kernel(
    const float* __restrict__ scores, const int* __restrict__ true_num,
    float* __restrict__ soft, float* __restrict__ out_soft) {
  const int h = blockIdx.x >> 3, b = blockIdx.x & 7;
  const int tid = threadIdx.x;
  const int tn = true_num[b];
  const float* s = scores + ((size_t)h * BBAG + b) * NINST;
  __shared__ float red[8];

  float vals[16];
  float mx = -3.0e38f;
  #pragma unroll
  for (int i = 0; i < 16; ++i) {
    int n = tid + i * 256;
    float v = s[n];
    vals[i] = (n < tn) ? v : -3.0e38f;
    mx = fmaxf(mx, vals[i]);
  }
  #pragma unroll
  for (int m = 1; m < 64; m <<= 1) mx = fmaxf(mx, __shfl_xor(mx, m));
  if ((tid & 63) == 0) red[tid >> 6] = mx;
  __syncthreads();
  mx = fmaxf(fmaxf(red[0], red[1]), fmaxf(red[2], red[3]));

  float sum = 0.f;
  #pragma unroll
  for (int i = 0; i < 16; ++i) {
    int n = tid + i * 256;
    float e = (n < tn) ? expf(vals[i] - mx) : 0.0f;
    vals[i] = e;
    sum += e;
  }
  #pragma unroll
  for (int m = 1; m < 64; m <<= 1) sum += __shfl_xor(sum, m);
  if ((tid & 63) == 0) red[4 + (tid >> 6)] = sum;
  __syncthreads();
  sum = red[4] + red[5] + red[6] + red[7];
  float inv = 1.0f / sum;

  float* so = soft + ((size_t)h * BBAG + b) * NINST;
  #pragma unroll
  for (int i = 0; i < 16; ++i) {
    int n = tid + i * 256;
    float v = vals[i] * inv;
    so[n] = v;
    if (h == 0) out_soft[(size_t)b * NINST + n] = v;
  }
}

// ---------------------------------------------------------------------------
// Kernel 5a: partial pooling. grid = (h,b,chunk): 8*8*8 = 512 blocks.
// ---------------------------------------------------------------------------
__global__ __launch_bounds__(256) void pool_partial(
    const short* __restrict__ mh, const float* __restrict__ soft,
    float* __restrict__ part) {
  const int c = blockIdx.x & (NCHUNK - 1);
  const int hb = blockIdx.x / NCHUNK;        // h*8 + b
  const int h = hb >> 3, b = hb & 7;
  const int tid = threadIdx.x;
  const int m = tid & 63, g = tid >> 6;
  const int n0 = c * (NINST / NCHUNK);
  const float* so = soft + ((size_t)h * BBAG + b) * NINST;
  const short* mp = mh + ((size_t)h * MTOT + (size_t)b * NINST) * DM;
  float acc = 0.f;
  #pragma unroll 4
  for (int n = n0 + g; n < n0 + NINST / NCHUNK; n += 4) {
    acc += so[n] * b2f(mp[(size_t)n * DM + m]);
  }
  __shared__ float red[256];
  red[tid] = acc;
  __syncthreads();
  if (tid < 64) {
    part[(size_t)(hb * NCHUNK + c) * DM + tid] =
        red[tid] + red[tid + 64] + red[tid + 128] + red[tid + 192];
  }
}

// ---------------------------------------------------------------------------
// Kernel 5b: reduce partials -> feat[b][h*64+m]
// ---------------------------------------------------------------------------
__global__ __launch_bounds__(256) void pool_reduce(
    const float* __restrict__ part, float* __restrict__ out_feat) {
  int g = blockIdx.x * blockDim.x + threadIdx.x;   // 4096 outputs
  int hb = g >> 6, m = g & 63;
  int h = hb >> 3, b = hb & 7;
  float s = 0.f;
  #pragma unroll
  for (int c = 0; c < NCHUNK; ++c)
    s += part[(size_t)(hb * NCHUNK + c) * DM + m];
  out_feat[(size_t)b * (NHEAD * DM) + h * DM + m] = s;
}

// ---------------------------------------------------------------------------
extern "C" void kernel_launch(void* const* d_in, const int* in_sizes, int n_in,
                              void* d_out, int out_size, void* d_ws, size_t ws_size,
                              hipStream_t stream) {
  (void)in_sizes; (void)n_in; (void)out_size; (void)ws_size;
  const float* x      = (const float*)d_in[0];
  const float* WX     = (const float*)d_in[1];
  const float* V      = (const float*)d_in[2];
  const float* W      = (const float*)d_in[3];
  const float* gate_w = (const float*)d_in[4];
  const int* true_num = (const int*)d_in[5];
  float* out = (float*)d_out;

  char* ws = (char*)d_ws;
  short* Wt2    = (short*)ws;  ws += (size_t)NCOL * DIM * 2;            //    655,360 B
  short* Vt     = (short*)ws;  ws += (size_t)DL * DM * 2;               //     16,384 B
  short* mh     = (short*)ws;  ws += (size_t)NHEAD * MTOT * DM * 2;     // 33,554,432 B
  short* gate   = (short*)ws;  ws += (size_t)MTOT * DL * 2;             //  8,388,608 B
  float* scores = (float*)ws;  ws += (size_t)NHEAD * MTOT * 4;          //  1,048,576 B
  float* soft   = (float*)ws;  ws += (size_t)NHEAD * MTOT * 4;          //  1,048,576 B
  float* part   = (float*)ws;  ws += (size_t)NHEAD * BBAG * NCHUNK * DM * 4; // 131,072 B

  prep_weights<<<dim3((16 * 640 * 4 + DL * DM + 255) / 256), dim3(256), 0, stream>>>(
      WX, V, gate_w, Wt2, Vt);
  proj_kernel<<<dim3(MTOT / 64), dim3(512), 0, stream>>>(x, Wt2, mh, gate);
  score_kernel<<<dim3(MTOT / 64), dim3(256), 0, stream>>>(mh, gate, Vt, W, scores);
  softmax_kernel<<<dim3(NHEAD * BBAG), dim3(256), 0, stream>>>(
      scores, true_num, soft, out + BBAG * NHEAD * DM);
  pool_partial<<<dim3(NHEAD * BBAG * NCHUNK), dim3(256), 0, stream>>>(mh, soft, part);
  pool_reduce<<<dim3(NHEAD * BBAG * DM / 256), dim3(256), 0, stream>>>(part, out);
}

// Round 8
// 106.587 us; speedup vs baseline: 1.3952x; 1.3952x over previous
//
#include <hip/hip_runtime.h>
#include <hip/hip_bf16.h>

#define DIM   512
#define NHEAD 8
#define DM    64
#define DL    128
#define BBAG  8
#define NINST 4096
#define MTOT  (BBAG*NINST)     // 32768 instances
#define NCOL  (NHEAD*DM + DL)  // 640 fused output columns (8*64 mh + 128 gate)
#define NCHUNK 8               // pool n-chunks per (h,b)

typedef short   bf16x8 __attribute__((ext_vector_type(8)));
typedef __bf16  bf16v8 __attribute__((ext_vector_type(8)));
typedef float   f32x4  __attribute__((ext_vector_type(4)));
typedef short   s16x4  __attribute__((ext_vector_type(4)));

__device__ __forceinline__ short f2b(float f) {
  __hip_bfloat16 h = __float2bfloat16(f);
  return __builtin_bit_cast(short, h);
}
__device__ __forceinline__ float b2f(short s) {
  __hip_bfloat16 h = __builtin_bit_cast(__hip_bfloat16, s);
  return __bfloat162float(h);
}
__device__ __forceinline__ f32x4 mfma_bf16(bf16x8 a, bf16x8 b, f32x4 c) {
  return __builtin_amdgcn_mfma_f32_16x16x32_bf16(
      __builtin_bit_cast(bf16v8, a), __builtin_bit_cast(bf16v8, b), c, 0, 0, 0);
}

// ---------------------------------------------------------------------------
// Kernel 1: build bf16 weights (slab-major, pre-swizzled; see R2 notes).
// Wt2 shorts[ks*20480 + col*32 + q2*8], q2 = (q + ((col&15)>>1)) & 3.
// Key property: for any (wave col-base, ct), the 64 lanes' fragment reads
// cover one CONTIGUOUS 1 KB block bijectively -> direct global->reg B loads
// are perfectly coalesced (no LDS needed for B).
// Vt[l][m] = V[m][l]
// ---------------------------------------------------------------------------
__global__ void prep_weights(const float* __restrict__ WX, const float* __restrict__ V,
                             const float* __restrict__ gate_w,
                             short* __restrict__ Wt2, short* __restrict__ Vt) {
  int g = blockIdx.x * blockDim.x + threadIdx.x;
  if (g < 16 * 640 * 4) {               // 40960 16-byte pieces of Wt2
    int ks = g / 2560;
    int rem = g - ks * 2560;
    int col = rem >> 2, q = rem & 3;
    int q2 = (q + ((col & 15) >> 1)) & 3;
    short* dst = Wt2 + ks * 20480 + col * 32 + q2 * 8;
    #pragma unroll
    for (int j = 0; j < 8; ++j) {
      int k = ks * 32 + q * 8 + j;
      float v;
      if (col < NHEAD * DM) v = WX[((size_t)(col >> 6) * DIM + k) * DM + (col & 63)];
      else                  v = gate_w[(size_t)k * DL + (col - NHEAD * DM)];
      dst[j] = f2b(v);
    }
  } else {
    int i = g - 16 * 640 * 4;
    if (i < DL * DM) {
      int l = i >> 6, m = i & 63;
      Vt[(size_t)l * DM + m] = f2b(V[(size_t)m * DL + l]);
    }
  }
}

// ---------------------------------------------------------------------------
// Kernel 2: fused projection GEMM  C[32768 x 640] = x[32768 x 512] * Wcat
// BM=128, grid=256 (exactly 1 block/CU, one round). 8 waves, wave w owns
// cols [80w,80w+80), all 128 rows -> acc[8][5] f32x4.
// A: staged ONCE in LDS (128 KB, swizzled 64B rows). B: NO LDS — direct
// coalesced global->reg loads, register double-buffered 1 iter ahead.
// K-loop has ZERO barriers; compiler's counted vmcnt covers the prefetch.
// ---------------------------------------------------------------------------
__global__ __launch_bounds__(512, 2) void proj_kernel(
    const float* __restrict__ x, const short* __restrict__ Wt2,
    short* __restrict__ mh, short* __restrict__ gate) {
  __shared__ alignas(16) short lds_a[65536];   // 128 KB: 16 slabs [128r][32k] swz
  const int tid = threadIdx.x;
  const int bm0 = blockIdx.x * 128;
  const int lane = tid & 63;
  const int w = tid >> 6;            // wave 0..7 -> cols [80w, 80w+80)
  const int r = lane & 15;
  const int q = lane >> 4;           // 0..3
  const int swzs = (q + (r >> 1)) & 3;        // swizzle slot for (r,q)
  char* lda = reinterpret_cast<char*>(lds_a);

  // ---- prologue: stage whole A tile (128 rows x 512 k) f32 -> bf16 LDS ----
  {
    const int row = tid >> 2, q4 = tid & 3;
    const int slot = (q4 + ((row & 15) >> 1)) & 3;
    const float* src = x + ((size_t)(bm0 + row) << 9) + (q4 << 3);
    char* dst = lda + row * 64 + slot * 16;
    #pragma unroll
    for (int ks = 0; ks < 16; ++ks) {
      f32x4 v0 = *reinterpret_cast<const f32x4*>(src + ks * 32);
      f32x4 v1 = *reinterpret_cast<const f32x4*>(src + ks * 32 + 4);
      bf16x8 bv;
      bv[0] = f2b(v0[0]); bv[1] = f2b(v0[1]); bv[2] = f2b(v0[2]); bv[3] = f2b(v0[3]);
      bv[4] = f2b(v1[0]); bv[5] = f2b(v1[1]); bv[6] = f2b(v1[2]); bv[7] = f2b(v1[3]);
      *reinterpret_cast<bf16x8*>(dst + ks * 8192) = bv;
    }
  }
  __syncthreads();

  // B-frag load: coalesced 1 KB wave-load per (ks, ct)
  const short* bbase = Wt2 + (80 * w + r) * 32 + swzs * 8;
  auto loadB = [&](int ks, bf16x8 bf[5]) {
    const short* p = bbase + ks * 20480;
    #pragma unroll
    for (int ct = 0; ct < 5; ++ct)
      bf[ct] = *reinterpret_cast<const bf16x8*>(p + ct * 512);
  };

  f32x4 acc[8][5];
  #pragma unroll
  for (int rt = 0; rt < 8; ++rt)
    #pragma unroll
    for (int ct = 0; ct < 5; ++ct) acc[rt][ct] = f32x4{0.f, 0.f, 0.f, 0.f};

  const int aoff = r * 64 + swzs * 16;
  auto compute = [&](int ks, bf16x8 bf[5]) {
    bf16x8 af[8];
    #pragma unroll
    for (int rt = 0; rt < 8; ++rt)
      af[rt] = *reinterpret_cast<const bf16x8*>(lda + ks * 8192 + rt * 1024 + aoff);
    #pragma unroll
    for (int ct = 0; ct < 5; ++ct)
      #pragma unroll
      for (int rt = 0; rt < 8; ++rt)
        acc[rt][ct] = mfma_bf16(af[rt], bf[ct], acc[rt][ct]);
  };

  bf16x8 bfA[5], bfB[5];
  loadB(0, bfA);
  for (int ks2 = 0; ks2 < 16; ks2 += 2) {
    loadB(ks2 + 1, bfB);          // prefetch odd step (regs)
    compute(ks2, bfA);            // MFMA hides bfB latency
    if (ks2 + 2 < 16) loadB(ks2 + 2, bfA);
    compute(ks2 + 1, bfB);
  }

  // epilogue: D-frag lane mapping row = 4q+j (+16rt), col = r (+16ct)
  #pragma unroll
  for (int rt = 0; rt < 8; ++rt) {
    #pragma unroll
    for (int ct = 0; ct < 5; ++ct) {
      int col = 80 * w + 16 * ct + r;
      #pragma unroll
      for (int j = 0; j < 4; ++j) {
        int grow = bm0 + 16 * rt + 4 * q + j;
        float v = acc[rt][ct][j];
        if (col < NHEAD * DM) {
          mh[((size_t)(col >> 6) * MTOT + grow) * DM + (col & 63)] = f2b(v);
        } else {
          gate[(size_t)grow * DL + (col - NHEAD * DM)] = f2b(1.0f / (1.0f + expf(-v)));
        }
      }
    }
  }
}

// ---------------------------------------------------------------------------
// Kernel 3: scores[h][row] = sum_l tanh( (mh_h . V)[row][l] ) * gate[row][l] * W[h][l]
// ---------------------------------------------------------------------------
__global__ __launch_bounds__(256) void score_kernel(
    const short* __restrict__ mh, const short* __restrict__ gate,
    const short* __restrict__ Vt, const float* __restrict__ W,
    float* __restrict__ scores) {
  const int tid = threadIdx.x;
  const int lane = tid & 63;
  const int wv = tid >> 6;         // 0..3
  const int r = lane & 15, q = lane >> 4;
  const int row0 = blockIdx.x * 64;

  #pragma unroll
  for (int hh = 0; hh < 2; ++hh) {
    const int h = wv * 2 + hh;
    float wc[8];
    #pragma unroll
    for (int ct = 0; ct < 8; ++ct) wc[ct] = W[(size_t)h * DL + 16 * ct + r];

    #pragma unroll
    for (int rt = 0; rt < 4; ++rt) {
      const short* ap = mh + ((size_t)h * MTOT + row0 + 16 * rt + r) * DM + q * 8;
      bf16x8 a0 = *reinterpret_cast<const bf16x8*>(ap);
      bf16x8 a1 = *reinterpret_cast<const bf16x8*>(ap + 32);
      float sc[4] = {0.f, 0.f, 0.f, 0.f};
      #pragma unroll
      for (int ct = 0; ct < 8; ++ct) {
        const short* bp = Vt + (size_t)(16 * ct + r) * DM + q * 8;
        bf16x8 b0 = *reinterpret_cast<const bf16x8*>(bp);
        bf16x8 b1 = *reinterpret_cast<const bf16x8*>(bp + 32);
        f32x4 t = f32x4{0.f, 0.f, 0.f, 0.f};
        t = mfma_bf16(a0, b0, t);
        t = mfma_bf16(a1, b1, t);
        #pragma unroll
        for (int j = 0; j < 4; ++j) {
          int row = row0 + 16 * rt + 4 * q + j;
          int coll = 16 * ct + r;
          float g = b2f(gate[(size_t)row * DL + coll]);
          float d = tanhf(t[j]) * g;
          sc[j] += d * wc[ct];
        }
      }
      #pragma unroll
      for (int j = 0; j < 4; ++j) {
        sc[j] += __shfl_xor(sc[j], 1);
        sc[j] += __shfl_xor(sc[j], 2);
        sc[j] += __shfl_xor(sc[j], 4);
        sc[j] += __shfl_xor(sc[j], 8);
      }
      if (r < 4) {
        float v = (r == 0) ? sc[0] : (r == 1) ? sc[1] : (r == 2) ? sc[2] : sc[3];
        scores[(size_t)h * MTOT + row0 + 16 * rt + 4 * q + r] = v;
      }
    }
  }
}

// ---------------------------------------------------------------------------
// Kernel 4: masked softmax over N per (h,b). soft=0 for n >= true_num[b].
// ---------------------------------------------------------------------------
__global__ __launch_bounds__(256) void softmax_kernel(
    const float* __restrict__ scores, const int* __restrict__ true_num,
    float* __restrict__ soft, float* __restrict__ out_soft) {
  const int h = blockIdx.x >> 3, b = blockIdx.x & 7;
  const int tid = threadIdx.x;
  const int tn = true_num[b];
  const float* s = scores + ((size_t)h * BBAG + b) * NINST;
  __shared__ float red[8];

  float vals[16];
  float mx = -3.0e38f;
  #pragma unroll
  for (int i = 0; i < 16; ++i) {
    int n = tid + i * 256;
    float v = s[n];
    vals[i] = (n < tn) ? v : -3.0e38f;
    mx = fmaxf(mx, vals[i]);
  }
  #pragma unroll
  for (int m = 1; m < 64; m <<= 1) mx = fmaxf(mx, __shfl_xor(mx, m));
  if ((tid & 63) == 0) red[tid >> 6] = mx;
  __syncthreads();
  mx = fmaxf(fmaxf(red[0], red[1]), fmaxf(red[2], red[3]));

  float sum = 0.f;
  #pragma unroll
  for (int i = 0; i < 16; ++i) {
    int n = tid + i * 256;
    float e = (n < tn) ? expf(vals[i] - mx) : 0.0f;
    vals[i] = e;
    sum += e;
  }
  #pragma unroll
  for (int m = 1; m < 64; m <<= 1) sum += __shfl_xor(sum, m);
  if ((tid & 63) == 0) red[4 + (tid >> 6)] = sum;
  __syncthreads();
  sum = red[4] + red[5] + red[6] + red[7];
  float inv = 1.0f / sum;

  float* so = soft + ((size_t)h * BBAG + b) * NINST;
  #pragma unroll
  for (int i = 0; i < 16; ++i) {
    int n = tid + i * 256;
    float v = vals[i] * inv;
    so[n] = v;
    if (h == 0) out_soft[(size_t)b * NINST + n] = v;
  }
}

// ---------------------------------------------------------------------------
// Kernel 5a: partial pooling. grid = (h,b,chunk): 8*8*8 = 512 blocks.
// ---------------------------------------------------------------------------
__global__ __launch_bounds__(256) void pool_partial(
    const short* __restrict__ mh, const float* __restrict__ soft,
    float* __restrict__ part) {
  const int c = blockIdx.x & (NCHUNK - 1);
  const int hb = blockIdx.x / NCHUNK;        // h*8 + b
  const int h = hb >> 3, b = hb & 7;
  const int tid = threadIdx.x;
  const int m = tid & 63, g = tid >> 6;
  const int n0 = c * (NINST / NCHUNK);
  const float* so = soft + ((size_t)h * BBAG + b) * NINST;
  const short* mp = mh + ((size_t)h * MTOT + (size_t)b * NINST) * DM;
  float acc = 0.f;
  #pragma unroll 4
  for (int n = n0 + g; n < n0 + NINST / NCHUNK; n += 4) {
    acc += so[n] * b2f(mp[(size_t)n * DM + m]);
  }
  __shared__ float red[256];
  red[tid] = acc;
  __syncthreads();
  if (tid < 64) {
    part[(size_t)(hb * NCHUNK + c) * DM + tid] =
        red[tid] + red[tid + 64] + red[tid + 128] + red[tid + 192];
  }
}

// ---------------------------------------------------------------------------
// Kernel 5b: reduce partials -> feat[b][h*64+m]
// ---------------------------------------------------------------------------
__global__ __launch_bounds__(256) void pool_reduce(
    const float* __restrict__ part, float* __restrict__ out_feat) {
  int g = blockIdx.x * blockDim.x + threadIdx.x;   // 4096 outputs
  int hb = g >> 6, m = g & 63;
  int h = hb >> 3, b = hb & 7;
  float s = 0.f;
  #pragma unroll
  for (int c = 0; c < NCHUNK; ++c)
    s += part[(size_t)(hb * NCHUNK + c) * DM + m];
  out_feat[(size_t)b * (NHEAD * DM) + h * DM + m] = s;
}

// ---------------------------------------------------------------------------
extern "C" void kernel_launch(void* const* d_in, const int* in_sizes, int n_in,
                              void* d_out, int out_size, void* d_ws, size_t ws_size,
                              hipStream_t stream) {
  (void)in_sizes; (void)n_in; (void)out_size; (void)ws_size;
  const float* x      = (const float*)d_in[0];
  const float* WX     = (const float*)d_in[1];
  const float* V      = (const float*)d_in[2];
  const float* W      = (const float*)d_in[3];
  const float* gate_w = (const float*)d_in[4];
  const int* true_num = (const int*)d_in[5];
  float* out = (float*)d_out;

  char* ws = (char*)d_ws;
  short* Wt2    = (short*)ws;  ws += (size_t)NCOL * DIM * 2;            //    655,360 B
  short* Vt     = (short*)ws;  ws += (size_t)DL * DM * 2;               //     16,384 B
  short* mh     = (short*)ws;  ws += (size_t)NHEAD * MTOT * DM * 2;     // 33,554,432 B
  short* gate   = (short*)ws;  ws += (size_t)MTOT * DL * 2;             //  8,388,608 B
  float* scores = (float*)ws;  ws += (size_t)NHEAD * MTOT * 4;          //  1,048,576 B
  float* soft   = (float*)ws;  ws += (size_t)NHEAD * MTOT * 4;          //  1,048,576 B
  float* part   = (float*)ws;  ws += (size_t)NHEAD * BBAG * NCHUNK * DM * 4; // 131,072 B

  prep_weights<<<dim3((16 * 640 * 4 + DL * DM + 255) / 256), dim3(256), 0, stream>>>(
      WX, V, gate_w, Wt2, Vt);
  proj_kernel<<<dim3(MTOT / 128), dim3(512), 0, stream>>>(x, Wt2, mh, gate);
  score_kernel<<<dim3(MTOT / 64), dim3(256), 0, stream>>>(mh, gate, Vt, W, scores);
  softmax_kernel<<<dim3(NHEAD * BBAG), dim3(256), 0, stream>>>(
      scores, true_num, soft, out + BBAG * NHEAD * DM);
  pool_partial<<<dim3(NHEAD * BBAG * NCHUNK), dim3(256), 0, stream>>>(mh, soft, part);
  pool_reduce<<<dim3(NHEAD * BBAG * DM / 256), dim3(256), 0, stream>>>(part, out);
}

// Round 9
// 106.512 us; speedup vs baseline: 1.3962x; 1.0007x over previous
//
#include <hip/hip_runtime.h>
#include <hip/hip_bf16.h>

#define DIM   512
#define NHEAD 8
#define DM    64
#define DL    128
#define BBAG  8
#define NINST 4096
#define MTOT  (BBAG*NINST)     // 32768 instances
#define NCOL  (NHEAD*DM + DL)  // 640 fused output columns (8*64 mh + 128 gate)
#define NCHUNK 8               // pool n-chunks per (h,b)

typedef short   bf16x8 __attribute__((ext_vector_type(8)));
typedef __bf16  bf16v8 __attribute__((ext_vector_type(8)));
typedef float   f32x4  __attribute__((ext_vector_type(4)));
typedef short   s16x4  __attribute__((ext_vector_type(4)));

__device__ __forceinline__ short f2b(float f) {
  __hip_bfloat16 h = __float2bfloat16(f);
  return __builtin_bit_cast(short, h);
}
__device__ __forceinline__ float b2f(short s) {
  __hip_bfloat16 h = __builtin_bit_cast(__hip_bfloat16, s);
  return __bfloat162float(h);
}
__device__ __forceinline__ f32x4 mfma_bf16(bf16x8 a, bf16x8 b, f32x4 c) {
  return __builtin_amdgcn_mfma_f32_16x16x32_bf16(
      __builtin_bit_cast(bf16v8, a), __builtin_bit_cast(bf16v8, b), c, 0, 0, 0);
}
__device__ __forceinline__ float fast_tanh(float x) {
  float t = __expf(2.0f * x);                       // v_exp_f32 path
  return 1.0f - 2.0f * __builtin_amdgcn_rcpf(t + 1.0f);
}
__device__ __forceinline__ float fast_sigmoid(float x) {
  return __builtin_amdgcn_rcpf(1.0f + __expf(-x));
}

// ---------------------------------------------------------------------------
// Kernel 1: build bf16 weights (slab-major, pre-swizzled; see R2 notes).
// Wt2 shorts[ks*20480 + col*32 + q2*8], q2 = (q + ((col&15)>>1)) & 3.
// 64 lanes' fragment reads of one (col16,ct) cover a contiguous 1 KB block
// bijectively -> direct global->reg B loads are coalesced (no LDS for B).
// Vt[l][m] = V[m][l]
// ---------------------------------------------------------------------------
__global__ void prep_weights(const float* __restrict__ WX, const float* __restrict__ V,
                             const float* __restrict__ gate_w,
                             short* __restrict__ Wt2, short* __restrict__ Vt) {
  int g = blockIdx.x * blockDim.x + threadIdx.x;
  if (g < 16 * 640 * 4) {               // 40960 16-byte pieces of Wt2
    int ks = g / 2560;
    int rem = g - ks * 2560;
    int col = rem >> 2, q = rem & 3;
    int q2 = (q + ((col & 15) >> 1)) & 3;
    short* dst = Wt2 + ks * 20480 + col * 32 + q2 * 8;
    #pragma unroll
    for (int j = 0; j < 8; ++j) {
      int k = ks * 32 + q * 8 + j;
      float v;
      if (col < NHEAD * DM) v = WX[((size_t)(col >> 6) * DIM + k) * DM + (col & 63)];
      else                  v = gate_w[(size_t)k * DL + (col - NHEAD * DM)];
      dst[j] = f2b(v);
    }
  } else {
    int i = g - 16 * 640 * 4;
    if (i < DL * DM) {
      int l = i >> 6, m = i & 63;
      Vt[(size_t)l * DM + m] = f2b(V[(size_t)m * DL + l]);
    }
  }
}

// ---------------------------------------------------------------------------
// Kernel 2: fused projection GEMM  C[32768 x 640] = x[32768 x 512] * Wcat
// BM=64, 1024 threads = 16 waves as 2(row)x8(col): wave tile 32x80 ->
// acc[2][5]=40 regs (total ~115, cap 128 => 4 waves/SIMD, 2 blocks/CU).
// A staged ONCE in LDS (64 KB swizzled). B direct global->reg, register
// double-buffered. ZERO barriers in K-loop. gate written TRANSPOSED.
// ---------------------------------------------------------------------------
__global__ __launch_bounds__(1024, 4) void proj_kernel(
    const float* __restrict__ x, const short* __restrict__ Wt2,
    short* __restrict__ mh, short* __restrict__ gate_t) {
  __shared__ alignas(16) short lds_a[32768];   // 64 KB: 16 slabs [64r][32k] swz
  const int tid = threadIdx.x;
  const int bm0 = blockIdx.x * 64;
  const int lane = tid & 63;
  const int w = tid >> 6;            // wave 0..15
  const int wr = w >> 3;             // 0..1 -> rows [32wr, 32wr+32)
  const int wc = w & 7;              // 0..7 -> cols [80wc, 80wc+80)
  const int r = lane & 15;
  const int q = lane >> 4;           // 0..3
  const int swzs = (q + (r >> 1)) & 3;
  char* lda = reinterpret_cast<char*>(lds_a);

  // ---- prologue: stage A tile (64 rows x 512 k) f32 -> bf16 LDS, swizzled.
  // threads 0-511 do slabs 0-7, threads 512-1023 do slabs 8-15.
  {
    const int row = (tid & 511) >> 3, p = tid & 7, half = tid >> 9;
    const int slot = ((p >> 1) + ((row & 15) >> 1)) & 3;
    const float* src = x + ((size_t)(bm0 + row) << 9) + (p << 2);
    char* dst = lda + row * 64 + slot * 16 + (p & 1) * 8;
    #pragma unroll
    for (int k8 = 0; k8 < 8; ++k8) {
      const int ks = half * 8 + k8;
      f32x4 v = *reinterpret_cast<const f32x4*>(src + ks * 32);
      s16x4 sv; sv.x = f2b(v[0]); sv.y = f2b(v[1]); sv.z = f2b(v[2]); sv.w = f2b(v[3]);
      *reinterpret_cast<s16x4*>(dst + ks * 4096) = sv;
    }
  }
  __syncthreads();

  // B-frag load: coalesced 1 KB wave-load per (ks, ct)
  const short* bbase = Wt2 + (80 * wc + r) * 32 + swzs * 8;
  auto loadB = [&](int ks, bf16x8 bf[5]) {
    const short* p = bbase + ks * 20480;
    #pragma unroll
    for (int ct = 0; ct < 5; ++ct)
      bf[ct] = *reinterpret_cast<const bf16x8*>(p + ct * 512);
  };

  f32x4 acc[2][5];
  #pragma unroll
  for (int rt = 0; rt < 2; ++rt)
    #pragma unroll
    for (int ct = 0; ct < 5; ++ct) acc[rt][ct] = f32x4{0.f, 0.f, 0.f, 0.f};

  const int aoff = (32 * wr + r) * 64 + swzs * 16;
  auto compute = [&](int ks, bf16x8 bf[5]) {
    bf16x8 af[2];
    #pragma unroll
    for (int rt = 0; rt < 2; ++rt)
      af[rt] = *reinterpret_cast<const bf16x8*>(lda + ks * 4096 + aoff + rt * 1024);
    #pragma unroll
    for (int ct = 0; ct < 5; ++ct)
      #pragma unroll
      for (int rt = 0; rt < 2; ++rt)
        acc[rt][ct] = mfma_bf16(af[rt], bf[ct], acc[rt][ct]);
  };

  bf16x8 bfA[5], bfB[5];
  loadB(0, bfA);
  for (int ks2 = 0; ks2 < 16; ks2 += 2) {
    loadB(ks2 + 1, bfB);          // prefetch odd step into regs
    compute(ks2, bfA);            // MFMA hides bfB latency
    if (ks2 + 2 < 16) loadB(ks2 + 2, bfA);
    compute(ks2 + 1, bfB);
  }

  // epilogue: D row = 32wr+16rt+4q+j, col = 80wc+16ct+r
  #pragma unroll
  for (int rt = 0; rt < 2; ++rt) {
    #pragma unroll
    for (int ct = 0; ct < 5; ++ct) {
      const int colbase = 80 * wc + 16 * ct;
      const int grow0 = bm0 + 32 * wr + 16 * rt + 4 * q;
      if (colbase < NHEAD * DM) {
        const int col = colbase + r;
        #pragma unroll
        for (int j = 0; j < 4; ++j)
          mh[((size_t)(col >> 6) * MTOT + grow0 + j) * DM + (col & 63)] =
              f2b(acc[rt][ct][j]);
      } else {
        const int l = colbase + r - NHEAD * DM;
        s16x4 gv;
        gv.x = f2b(fast_sigmoid(acc[rt][ct][0]));
        gv.y = f2b(fast_sigmoid(acc[rt][ct][1]));
        gv.z = f2b(fast_sigmoid(acc[rt][ct][2]));
        gv.w = f2b(fast_sigmoid(acc[rt][ct][3]));
        *reinterpret_cast<s16x4*>(gate_t + (size_t)l * MTOT + grow0) = gv;
      }
    }
  }
}

// ---------------------------------------------------------------------------
// Kernel 3: scores[h][row] = sum_l tanh( (mh_h . V)[row][l] ) * gate[row][l] * W[h][l]
// fast_tanh (exp2-based) + transposed gate (s16x4 vector loads).
// ---------------------------------------------------------------------------
__global__ __launch_bounds__(256) void score_kernel(
    const short* __restrict__ mh, const short* __restrict__ gate_t,
    const short* __restrict__ Vt, const float* __restrict__ W,
    float* __restrict__ scores) {
  const int tid = threadIdx.x;
  const int lane = tid & 63;
  const int wv = tid >> 6;         // 0..3
  const int r = lane & 15, q = lane >> 4;
  const int row0 = blockIdx.x * 64;

  #pragma unroll
  for (int hh = 0; hh < 2; ++hh) {
    const int h = wv * 2 + hh;
    float wc[8];
    #pragma unroll
    for (int ct = 0; ct < 8; ++ct) wc[ct] = W[(size_t)h * DL + 16 * ct + r];

    #pragma unroll
    for (int rt = 0; rt < 4; ++rt) {
      const short* ap = mh + ((size_t)h * MTOT + row0 + 16 * rt + r) * DM + q * 8;
      bf16x8 a0 = *reinterpret_cast<const bf16x8*>(ap);
      bf16x8 a1 = *reinterpret_cast<const bf16x8*>(ap + 32);
      float sc[4] = {0.f, 0.f, 0.f, 0.f};
      #pragma unroll
      for (int ct = 0; ct < 8; ++ct) {
        const short* bp = Vt + (size_t)(16 * ct + r) * DM + q * 8;
        bf16x8 b0 = *reinterpret_cast<const bf16x8*>(bp);
        bf16x8 b1 = *reinterpret_cast<const bf16x8*>(bp + 32);
        f32x4 t = f32x4{0.f, 0.f, 0.f, 0.f};
        t = mfma_bf16(a0, b0, t);
        t = mfma_bf16(a1, b1, t);
        s16x4 ga = *reinterpret_cast<const s16x4*>(
            gate_t + (size_t)(16 * ct + r) * MTOT + row0 + 16 * rt + 4 * q);
        #pragma unroll
        for (int j = 0; j < 4; ++j) {
          float g = b2f((j == 0) ? ga.x : (j == 1) ? ga.y : (j == 2) ? ga.z : ga.w);
          sc[j] += fast_tanh(t[j]) * g * wc[ct];
        }
      }
      #pragma unroll
      for (int j = 0; j < 4; ++j) {
        sc[j] += __shfl_xor(sc[j], 1);
        sc[j] += __shfl_xor(sc[j], 2);
        sc[j] += __shfl_xor(sc[j], 4);
        sc[j] += __shfl_xor(sc[j], 8);
      }
      if (r < 4) {
        float v = (r == 0) ? sc[0] : (r == 1) ? sc[1] : (r == 2) ? sc[2] : sc[3];
        scores[(size_t)h * MTOT + row0 + 16 * rt + 4 * q + r] = v;
      }
    }
  }
}

// ---------------------------------------------------------------------------
// Kernel 4: masked softmax over N per (h,b). soft=0 for n >= true_num[b].
// ---------------------------------------------------------------------------
__global__ __launch_bounds__(256) void softmax_kernel(
    const float* __restrict__ scores, const int* __restrict__ true_num,
    float* __restrict__ soft, float* __restrict__ out_soft) {
  const int h = blockIdx.x >> 3, b = blockIdx.x & 7;
  const int tid = threadIdx.x;
  const int tn = true_num[b];
  const float* s = scores + ((size_t)h * BBAG + b) * NINST;
  __shared__ float red[8];

  float vals[16];
  float mx = -3.0e38f;
  #pragma unroll
  for (int i = 0; i < 16; ++i) {
    int n = tid + i * 256;
    float v = s[n];
    vals[i] = (n < tn) ? v : -3.0e38f;
    mx = fmaxf(mx, vals[i]);
  }
  #pragma unroll
  for (int m = 1; m < 64; m <<= 1) mx = fmaxf(mx, __shfl_xor(mx, m));
  if ((tid & 63) == 0) red[tid >> 6] = mx;
  __syncthreads();
  mx = fmaxf(fmaxf(red[0], red[1]), fmaxf(red[2], red[3]));

  float sum = 0.f;
  #pragma unroll
  for (int i = 0; i < 16; ++i) {
    int n = tid + i * 256;
    float e = (n < tn) ? expf(vals[i] - mx) : 0.0f;
    vals[i] = e;
    sum += e;
  }
  #pragma unroll
  for (int m = 1; m < 64; m <<= 1) sum += __shfl_xor(sum, m);
  if ((tid & 63) == 0) red[4 + (tid >> 6)] = sum;
  __syncthreads();
  sum = red[4] + red[5] + red[6] + red[7];
  float inv = 1.0f / sum;

  float* so = soft + ((size_t)h * BBAG + b) * NINST;
  #pragma unroll
  for (int i = 0; i < 16; ++i) {
    int n = tid + i * 256;
    float v = vals[i] * inv;
    so[n] = v;
    if (h == 0) out_soft[(size_t)b * NINST + n] = v;
  }
}

// ---------------------------------------------------------------------------
// Kernel 5a: partial pooling. grid = (h,b,chunk): 8*8*8 = 512 blocks.
// ---------------------------------------------------------------------------
__global__ __launch_bounds__(256) void pool_partial(
    const short* __restrict__ mh, const float* __restrict__ soft,
    float* __restrict__ part) {
  const int c = blockIdx.x & (NCHUNK - 1);
  const int hb = blockIdx.x / NCHUNK;        // h*8 + b
  const int h = hb >> 3, b = hb & 7;
  const int tid = threadIdx.x;
  const int m = tid & 63, g = tid >> 6;
  const int n0 = c * (NINST / NCHUNK);
  const float* so = soft + ((size_t)h * BBAG + b) * NINST;
  const short* mp = mh + ((size_t)h * MTOT + (size_t)b * NINST) * DM;
  float acc = 0.f;
  #pragma unroll 4
  for (int n = n0 + g; n < n0 + NINST / NCHUNK; n += 4) {
    acc += so[n] * b2f(mp[(size_t)n * DM + m]);
  }
  __shared__ float red[256];
  red[tid] = acc;
  __syncthreads();
  if (tid < 64) {
    part[(size_t)(hb * NCHUNK + c) * DM + tid] =
        red[tid] + red[tid + 64] + red[tid + 128] + red[tid + 192];
  }
}

// ---------------------------------------------------------------------------
// Kernel 5b: reduce partials -> feat[b][h*64+m]
// ---------------------------------------------------------------------------
__global__ __launch_bounds__(256) void pool_reduce(
    const float* __restrict__ part, float* __restrict__ out_feat) {
  int g = blockIdx.x * blockDim.x + threadIdx.x;   // 4096 outputs
  int hb = g >> 6, m = g & 63;
  int h = hb >> 3, b = hb & 7;
  float s = 0.f;
  #pragma unroll
  for (int c = 0; c < NCHUNK; ++c)
    s += part[(size_t)(hb * NCHUNK + c) * DM + m];
  out_feat[(size_t)b * (NHEAD * DM) + h * DM + m] = s;
}

// ---------------------------------------------------------------------------
extern "C" void kernel_launch(void* const* d_in, const int* in_sizes, int n_in,
                              void* d_out, int out_size, void* d_ws, size_t ws_size,
                              hipStream_t stream) {
  (void)in_sizes; (void)n_in; (void)out_size; (void)ws_size;
  const float* x      = (const float*)d_in[0];
  const float* WX     = (const float*)d_in[1];
  const float* V      = (const float*)d_in[2];
  const float* W      = (const float*)d_in[3];
  const float* gate_w = (const float*)d_in[4];
  const int* true_num = (const int*)d_in[5];
  float* out = (float*)d_out;

  char* ws = (char*)d_ws;
  short* Wt2    = (short*)ws;  ws += (size_t)NCOL * DIM * 2;            //    655,360 B
  short* Vt     = (short*)ws;  ws += (size_t)DL * DM * 2;               //     16,384 B
  short* mh     = (short*)ws;  ws += (size_t)NHEAD * MTOT * DM * 2;     // 33,554,432 B
  short* gate_t = (short*)ws;  ws += (size_t)DL * MTOT * 2;             //  8,388,608 B
  float* scores = (float*)ws;  ws += (size_t)NHEAD * MTOT * 4;          //  1,048,576 B
  float* soft   = (float*)ws;  ws += (size_t)NHEAD * MTOT * 4;          //  1,048,576 B
  float* part   = (float*)ws;  ws += (size_t)NHEAD * BBAG * NCHUNK * DM * 4; // 131,072 B

  prep_weights<<<dim3((16 * 640 * 4 + DL * DM + 255) / 256), dim3(256), 0, stream>>>(
      WX, V, gate_w, Wt2, Vt);
  proj_kernel<<<dim3(MTOT / 64), dim3(1024), 0, stream>>>(x, Wt2, mh, gate_t);
  score_kernel<<<dim3(MTOT / 64), dim3(256), 0, stream>>>(mh, gate_t, Vt, W, scores);
  softmax_kernel<<<dim3(NHEAD * BBAG), dim3(256), 0, stream>>>(
      scores, true_num, soft, out + BBAG * NHEAD * DM);
  pool_partial<<<dim3(NHEAD * BBAG * NCHUNK), dim3(256), 0, stream>>>(mh, soft, part);
  pool_reduce<<<dim3(NHEAD * BBAG * DM / 256), dim3(256), 0, stream>>>(part, out);
}

// Round 10
// 105.108 us; speedup vs baseline: 1.4148x; 1.0134x over previous
//
#include <hip/hip_runtime.h>
#include <hip/hip_bf16.h>

#define DIM   512
#define NHEAD 8
#define DM    64
#define DL    128
#define BBAG  8
#define NINST 4096
#define MTOT  (BBAG*NINST)     // 32768 instances
#define NCOL  (NHEAD*DM + DL)  // 640 fused output columns (8*64 mh + 128 gate)
#define NCHUNK 8               // pool n-chunks per (h,b)

typedef short   bf16x8 __attribute__((ext_vector_type(8)));
typedef __bf16  bf16v8 __attribute__((ext_vector_type(8)));
typedef float   f32x4  __attribute__((ext_vector_type(4)));
typedef short   s16x4  __attribute__((ext_vector_type(4)));

__device__ __forceinline__ short f2b(float f) {
  __hip_bfloat16 h = __float2bfloat16(f);
  return __builtin_bit_cast(short, h);
}
__device__ __forceinline__ float b2f(short s) {
  __hip_bfloat16 h = __builtin_bit_cast(__hip_bfloat16, s);
  return __bfloat162float(h);
}
__device__ __forceinline__ f32x4 mfma_bf16(bf16x8 a, bf16x8 b, f32x4 c) {
  return __builtin_amdgcn_mfma_f32_16x16x32_bf16(
      __builtin_bit_cast(bf16v8, a), __builtin_bit_cast(bf16v8, b), c, 0, 0, 0);
}
__device__ __forceinline__ float fast_tanh(float x) {
  float t = __expf(2.0f * x);
  return 1.0f - 2.0f * __builtin_amdgcn_rcpf(t + 1.0f);
}
__device__ __forceinline__ float fast_sigmoid(float x) {
  return __builtin_amdgcn_rcpf(1.0f + __expf(-x));
}

// ---------------------------------------------------------------------------
// Kernel 1 (REWRITTEN): build Wt2/Vt with coalesced LDS-transpose.
// Wt2 layout unchanged: shorts[ks*20480 + col*32 + q2*8], q2=(q+((col&15)>>1))&3.
// blocks 0..127: (h,ks) tiles of WX; 128..143: gate_w per ks; 144: Vt.
// ---------------------------------------------------------------------------
__global__ __launch_bounds__(256) void prep_weights(
    const float* __restrict__ WX, const float* __restrict__ V,
    const float* __restrict__ gate_w,
    short* __restrict__ Wt2, short* __restrict__ Vt) {
  __shared__ float lds[32 * 129];
  const int bid = blockIdx.x, t = threadIdx.x;

  if (bid < 128) {
    // ---- WX part: block = (h, ks); tile 32k x 64m ----
    const int h = bid >> 4, ks = bid & 15;
    {
      const int kl = t >> 3, m8 = (t & 7) * 8;
      const float* src = WX + ((size_t)(h * DIM + ks * 32 + kl) * DM + m8);
      #pragma unroll
      for (int j = 0; j < 8; ++j) lds[kl * 129 + m8 + j] = src[j];
    }
    __syncthreads();
    {
      const int m = t >> 2, q = t & 3;
      const int col = h * 64 + m;
      const int q2 = (q + ((col & 15) >> 1)) & 3;
      short* dst = Wt2 + ks * 20480 + col * 32 + q2 * 8;
      #pragma unroll
      for (int j = 0; j < 8; ++j) dst[j] = f2b(lds[(q * 8 + j) * 129 + m]);
    }
  } else if (bid < 144) {
    // ---- gate_w part: block = ks; tile 32k x 128l ----
    const int ks = bid - 128;
    #pragma unroll
    for (int rep = 0; rep < 2; ++rep) {
      const int idx = rep * 2048 + t * 8;
      const int kl = idx >> 7, l8 = idx & 127;
      const float* src = gate_w + ((size_t)(ks * 32 + kl) * DL + l8);
      #pragma unroll
      for (int j = 0; j < 8; ++j) lds[kl * 129 + l8 + j] = src[j];
    }
    __syncthreads();
    #pragma unroll
    for (int rep = 0; rep < 2; ++rep) {
      const int piece = rep * 256 + t;
      const int l = piece >> 2, q = piece & 3;
      const int col = 512 + l;
      const int q2 = (q + ((col & 15) >> 1)) & 3;
      short* dst = Wt2 + ks * 20480 + col * 32 + q2 * 8;
      #pragma unroll
      for (int j = 0; j < 8; ++j) dst[j] = f2b(lds[(q * 8 + j) * 129 + l]);
    }
  } else {
    // ---- Vt[l][m] = V[m][l] (small, 8192 elems) ----
    for (int r = 0; r < 32; ++r) {
      int i = t + r * 256;
      int l = i >> 6, m = i & 63;
      Vt[(size_t)l * DM + m] = f2b(V[(size_t)m * DL + l]);
    }
  }
}

// ---------------------------------------------------------------------------
// Kernel 2: fused projection GEMM  C[32768 x 640] = x[32768 x 512] * Wcat
// BM=64, 1024 thr = 16 waves (2 row x 8 col), wave tile 32x80, acc[2][5].
// DEPTH-2 register pipeline: 3 B-buffers (global->reg, coalesced 1KB
// wave-loads from pre-swizzled Wt2) + double-buffered A-frags (LDS).
// Fully-unrolled K-loop, static buffer indices, ZERO barriers in loop.
// ---------------------------------------------------------------------------
__global__ __launch_bounds__(1024, 4) void proj_kernel(
    const float* __restrict__ x, const short* __restrict__ Wt2,
    short* __restrict__ mh, short* __restrict__ gate_t) {
  __shared__ alignas(16) short lds_a[32768];   // 64 KB: 16 slabs [64r][32k] swz
  const int tid = threadIdx.x;
  const int bm0 = blockIdx.x * 64;
  const int lane = tid & 63;
  const int w = tid >> 6;            // wave 0..15
  const int wr = w >> 3;             // 0..1 -> rows [32wr, 32wr+32)
  const int wc = w & 7;              // 0..7 -> cols [80wc, 80wc+80)
  const int r = lane & 15;
  const int q = lane >> 4;           // 0..3
  const int swzs = (q + (r >> 1)) & 3;
  char* lda = reinterpret_cast<char*>(lds_a);

  // ---- prologue: stage A tile (64 rows x 512 k) f32 -> bf16 LDS, swizzled.
  {
    const int row = (tid & 511) >> 3, p = tid & 7, half = tid >> 9;
    const int slot = ((p >> 1) + ((row & 15) >> 1)) & 3;
    const float* src = x + ((size_t)(bm0 + row) << 9) + (p << 2);
    char* dst = lda + row * 64 + slot * 16 + (p & 1) * 8;
    #pragma unroll
    for (int k8 = 0; k8 < 8; ++k8) {
      const int ks = half * 8 + k8;
      f32x4 v = *reinterpret_cast<const f32x4*>(src + ks * 32);
      s16x4 sv; sv.x = f2b(v[0]); sv.y = f2b(v[1]); sv.z = f2b(v[2]); sv.w = f2b(v[3]);
      *reinterpret_cast<s16x4*>(dst + ks * 4096) = sv;
    }
  }

  const short* bbase = Wt2 + (80 * wc + r) * 32 + swzs * 8;
  const int aoff = (32 * wr + r) * 64 + swzs * 16;

  bf16x8 bufs[3][5];     // B triple buffer (static idx after unroll)
  bf16x8 afb[2][2];      // A-frag double buffer

  // B prefetch for ks=0,1 issued BEFORE the barrier (global->reg, no LDS dep)
  #pragma unroll
  for (int ct = 0; ct < 5; ++ct)
    bufs[0][ct] = *reinterpret_cast<const bf16x8*>(bbase + 0 * 20480 + ct * 512);
  #pragma unroll
  for (int ct = 0; ct < 5; ++ct)
    bufs[1][ct] = *reinterpret_cast<const bf16x8*>(bbase + 1 * 20480 + ct * 512);

  __syncthreads();

  // A-frag for ks=0
  #pragma unroll
  for (int rt = 0; rt < 2; ++rt)
    afb[0][rt] = *reinterpret_cast<const bf16x8*>(lda + 0 * 4096 + aoff + rt * 1024);

  f32x4 acc[2][5];
  #pragma unroll
  for (int rt = 0; rt < 2; ++rt)
    #pragma unroll
    for (int ct = 0; ct < 5; ++ct) acc[rt][ct] = f32x4{0.f, 0.f, 0.f, 0.f};

  #pragma unroll
  for (int ks = 0; ks < 16; ++ks) {
    if (ks + 2 < 16) {
      #pragma unroll
      for (int ct = 0; ct < 5; ++ct)
        bufs[(ks + 2) % 3][ct] = *reinterpret_cast<const bf16x8*>(
            bbase + (ks + 2) * 20480 + ct * 512);
    }
    if (ks + 1 < 16) {
      #pragma unroll
      for (int rt = 0; rt < 2; ++rt)
        afb[(ks + 1) & 1][rt] = *reinterpret_cast<const bf16x8*>(
            lda + (ks + 1) * 4096 + aoff + rt * 1024);
    }
    #pragma unroll
    for (int ct = 0; ct < 5; ++ct)
      #pragma unroll
      for (int rt = 0; rt < 2; ++rt)
        acc[rt][ct] = mfma_bf16(afb[ks & 1][rt], bufs[ks % 3][ct], acc[rt][ct]);
  }

  // epilogue: D row = 32wr+16rt+4q+j, col = 80wc+16ct+r
  #pragma unroll
  for (int rt = 0; rt < 2; ++rt) {
    #pragma unroll
    for (int ct = 0; ct < 5; ++ct) {
      const int colbase = 80 * wc + 16 * ct;
      const int grow0 = bm0 + 32 * wr + 16 * rt + 4 * q;
      if (colbase < NHEAD * DM) {
        const int col = colbase + r;
        #pragma unroll
        for (int j = 0; j < 4; ++j)
          mh[((size_t)(col >> 6) * MTOT + grow0 + j) * DM + (col & 63)] =
              f2b(acc[rt][ct][j]);
      } else {
        const int l = colbase + r - NHEAD * DM;
        s16x4 gv;
        gv.x = f2b(fast_sigmoid(acc[rt][ct][0]));
        gv.y = f2b(fast_sigmoid(acc[rt][ct][1]));
        gv.z = f2b(fast_sigmoid(acc[rt][ct][2]));
        gv.w = f2b(fast_sigmoid(acc[rt][ct][3]));
        *reinterpret_cast<s16x4*>(gate_t + (size_t)l * MTOT + grow0) = gv;
      }
    }
  }
}

// ---------------------------------------------------------------------------
// Kernel 3: scores[h][row] = sum_l tanh( (mh_h . V)[row][l] ) * gate[row][l] * W[h][l]
// ---------------------------------------------------------------------------
__global__ __launch_bounds__(256) void score_kernel(
    const short* __restrict__ mh, const short* __restrict__ gate_t,
    const short* __restrict__ Vt, const float* __restrict__ W,
    float* __restrict__ scores) {
  const int tid = threadIdx.x;
  const int lane = tid & 63;
  const int wv = tid >> 6;         // 0..3
  const int r = lane & 15, q = lane >> 4;
  const int row0 = blockIdx.x * 64;

  #pragma unroll
  for (int hh = 0; hh < 2; ++hh) {
    const int h = wv * 2 + hh;
    float wc[8];
    #pragma unroll
    for (int ct = 0; ct < 8; ++ct) wc[ct] = W[(size_t)h * DL + 16 * ct + r];

    #pragma unroll
    for (int rt = 0; rt < 4; ++rt) {
      const short* ap = mh + ((size_t)h * MTOT + row0 + 16 * rt + r) * DM + q * 8;
      bf16x8 a0 = *reinterpret_cast<const bf16x8*>(ap);
      bf16x8 a1 = *reinterpret_cast<const bf16x8*>(ap + 32);
      float sc[4] = {0.f, 0.f, 0.f, 0.f};
      #pragma unroll
      for (int ct = 0; ct < 8; ++ct) {
        const short* bp = Vt + (size_t)(16 * ct + r) * DM + q * 8;
        bf16x8 b0 = *reinterpret_cast<const bf16x8*>(bp);
        bf16x8 b1 = *reinterpret_cast<const bf16x8*>(bp + 32);
        f32x4 t = f32x4{0.f, 0.f, 0.f, 0.f};
        t = mfma_bf16(a0, b0, t);
        t = mfma_bf16(a1, b1, t);
        s16x4 ga = *reinterpret_cast<const s16x4*>(
            gate_t + (size_t)(16 * ct + r) * MTOT + row0 + 16 * rt + 4 * q);
        #pragma unroll
        for (int j = 0; j < 4; ++j) {
          float g = b2f((j == 0) ? ga.x : (j == 1) ? ga.y : (j == 2) ? ga.z : ga.w);
          sc[j] += fast_tanh(t[j]) * g * wc[ct];
        }
      }
      #pragma unroll
      for (int j = 0; j < 4; ++j) {
        sc[j] += __shfl_xor(sc[j], 1);
        sc[j] += __shfl_xor(sc[j], 2);
        sc[j] += __shfl_xor(sc[j], 4);
        sc[j] += __shfl_xor(sc[j], 8);
      }
      if (r < 4) {
        float v = (r == 0) ? sc[0] : (r == 1) ? sc[1] : (r == 2) ? sc[2] : sc[3];
        scores[(size_t)h * MTOT + row0 + 16 * rt + 4 * q + r] = v;
      }
    }
  }
}

// ---------------------------------------------------------------------------
// Kernel 4: masked softmax over N per (h,b). soft=0 for n >= true_num[b].
// ---------------------------------------------------------------------------
__global__ __launch_bounds__(256) void softmax_kernel(
    const float* __restrict__ scores, const int* __restrict__ true_num,
    float* __restrict__ soft, float* __restrict__ out_soft) {
  const int h = blockIdx.x >> 3, b = blockIdx.x & 7;
  const int tid = threadIdx.x;
  const int tn = true_num[b];
  const float* s = scores + ((size_t)h * BBAG + b) * NINST;
  __shared__ float red[8];

  float vals[16];
  float mx = -3.0e38f;
  #pragma unroll
  for (int i = 0; i < 16; ++i) {
    int n = tid + i * 256;
    float v = s[n];
    vals[i] = (n < tn) ? v : -3.0e38f;
    mx = fmaxf(mx, vals[i]);
  }
  #pragma unroll
  for (int m = 1; m < 64; m <<= 1) mx = fmaxf(mx, __shfl_xor(mx, m));
  if ((tid & 63) == 0) red[tid >> 6] = mx;
  __syncthreads();
  mx = fmaxf(fmaxf(red[0], red[1]), fmaxf(red[2], red[3]));

  float sum = 0.f;
  #pragma unroll
  for (int i = 0; i < 16; ++i) {
    int n = tid + i * 256;
    float e = (n < tn) ? expf(vals[i] - mx) : 0.0f;
    vals[i] = e;
    sum += e;
  }
  #pragma unroll
  for (int m = 1; m < 64; m <<= 1) sum += __shfl_xor(sum, m);
  if ((tid & 63) == 0) red[4 + (tid >> 6)] = sum;
  __syncthreads();
  sum = red[4] + red[5] + red[6] + red[7];
  float inv = 1.0f / sum;

  float* so = soft + ((size_t)h * BBAG + b) * NINST;
  #pragma unroll
  for (int i = 0; i < 16; ++i) {
    int n = tid + i * 256;
    float v = vals[i] * inv;
    so[n] = v;
    if (h == 0) out_soft[(size_t)b * NINST + n] = v;
  }
}

// ---------------------------------------------------------------------------
// Kernel 5a: partial pooling. grid = (h,b,chunk): 8*8*8 = 512 blocks.
// ---------------------------------------------------------------------------
__global__ __launch_bounds__(256) void pool_partial(
    const short* __restrict__ mh, const float* __restrict__ soft,
    float* __restrict__ part) {
  const int c = blockIdx.x & (NCHUNK - 1);
  const int hb = blockIdx.x / NCHUNK;        // h*8 + b
  const int h = hb >> 3, b = hb & 7;
  const int tid = threadIdx.x;
  const int m = tid & 63, g = tid >> 6;
  const int n0 = c * (NINST / NCHUNK);
  const float* so = soft + ((size_t)h * BBAG + b) * NINST;
  const short* mp = mh + ((size_t)h * MTOT + (size_t)b * NINST) * DM;
  float acc = 0.f;
  #pragma unroll 4
  for (int n = n0 + g; n < n0 + NINST / NCHUNK; n += 4) {
    acc += so[n] * b2f(mp[(size_t)n * DM + m]);
  }
  __shared__ float red[256];
  red[tid] = acc;
  __syncthreads();
  if (tid < 64) {
    part[(size_t)(hb * NCHUNK + c) * DM + tid] =
        red[tid] + red[tid + 64] + red[tid + 128] + red[tid + 192];
  }
}

// ---------------------------------------------------------------------------
// Kernel 5b: reduce partials -> feat[b][h*64+m]
// ---------------------------------------------------------------------------
__global__ __launch_bounds__(256) void pool_reduce(
    const float* __restrict__ part, float* __restrict__ out_feat) {
  int g = blockIdx.x * blockDim.x + threadIdx.x;   // 4096 outputs
  int hb = g >> 6, m = g & 63;
  int h = hb >> 3, b = hb & 7;
  float s = 0.f;
  #pragma unroll
  for (int c = 0; c < NCHUNK; ++c)
    s += part[(size_t)(hb * NCHUNK + c) * DM + m];
  out_feat[(size_t)b * (NHEAD * DM) + h * DM + m] = s;
}

// ---------------------------------------------------------------------------
extern "C" void kernel_launch(void* const* d_in, const int* in_sizes, int n_in,
                              void* d_out, int out_size, void* d_ws, size_t ws_size,
                              hipStream_t stream) {
  (void)in_sizes; (void)n_in; (void)out_size; (void)ws_size;
  const float* x      = (const float*)d_in[0];
  const float* WX     = (const float*)d_in[1];
  const float* V      = (const float*)d_in[2];
  const float* W      = (const float*)d_in[3];
  const float* gate_w = (const float*)d_in[4];
  const int* true_num = (const int*)d_in[5];
  float* out = (float*)d_out;

  char* ws = (char*)d_ws;
  short* Wt2    = (short*)ws;  ws += (size_t)NCOL * DIM * 2;            //    655,360 B
  short* Vt     = (short*)ws;  ws += (size_t)DL * DM * 2;               //     16,384 B
  short* mh     = (short*)ws;  ws += (size_t)NHEAD * MTOT * DM * 2;     // 33,554,432 B
  short* gate_t = (short*)ws;  ws += (size_t)DL * MTOT * 2;             //  8,388,608 B
  float* scores = (float*)ws;  ws += (size_t)NHEAD * MTOT * 4;          //  1,048,576 B
  float* soft   = (float*)ws;  ws += (size_t)NHEAD * MTOT * 4;          //  1,048,576 B
  float* part   = (float*)ws;  ws += (size_t)NHEAD * BBAG * NCHUNK * DM * 4; // 131,072 B

  prep_weights<<<dim3(145), dim3(256), 0, stream>>>(WX, V, gate_w, Wt2, Vt);
  proj_kernel<<<dim3(MTOT / 64), dim3(1024), 0, stream>>>(x, Wt2, mh, gate_t);
  score_kernel<<<dim3(MTOT / 64), dim3(256), 0, stream>>>(mh, gate_t, Vt, W, scores);
  softmax_kernel<<<dim3(NHEAD * BBAG), dim3(256), 0, stream>>>(
      scores, true_num, soft, out + BBAG * NHEAD * DM);
  pool_partial<<<dim3(NHEAD * BBAG * NCHUNK), dim3(256), 0, stream>>>(mh, soft, part);
  pool_reduce<<<dim3(NHEAD * BBAG * DM / 256), dim3(256), 0, stream>>>(part, out);
}

// Round 11
// 103.123 us; speedup vs baseline: 1.4420x; 1.0192x over previous
//
#include <hip/hip_runtime.h>
#include <hip/hip_bf16.h>

#define DIM   512
#define NHEAD 8
#define DM    64
#define DL    128
#define BBAG  8
#define NINST 4096
#define MTOT  (BBAG*NINST)     // 32768 instances
#define NCOL  (NHEAD*DM + DL)  // 640 fused output columns (8*64 mh + 128 gate)
#define NCHUNK 8               // pool n-chunks per (h,b)

typedef short   bf16x8 __attribute__((ext_vector_type(8)));
typedef __bf16  bf16v8 __attribute__((ext_vector_type(8)));
typedef float   f32x4  __attribute__((ext_vector_type(4)));
typedef short   s16x4  __attribute__((ext_vector_type(4)));

__device__ __forceinline__ short f2b(float f) {
  __hip_bfloat16 h = __float2bfloat16(f);
  return __builtin_bit_cast(short, h);
}
__device__ __forceinline__ float b2f(short s) {
  __hip_bfloat16 h = __builtin_bit_cast(__hip_bfloat16, s);
  return __bfloat162float(h);
}
__device__ __forceinline__ f32x4 mfma_bf16(bf16x8 a, bf16x8 b, f32x4 c) {
  return __builtin_amdgcn_mfma_f32_16x16x32_bf16(
      __builtin_bit_cast(bf16v8, a), __builtin_bit_cast(bf16v8, b), c, 0, 0, 0);
}
__device__ __forceinline__ float fast_tanh(float x) {
  float t = __expf(2.0f * x);
  return 1.0f - 2.0f * __builtin_amdgcn_rcpf(t + 1.0f);
}
__device__ __forceinline__ float fast_sigmoid(float x) {
  return __builtin_amdgcn_rcpf(1.0f + __expf(-x));
}

// ---------------------------------------------------------------------------
// Kernel 1: build Wt2/Vt with coalesced LDS-transpose (R9, validated).
// Wt2: shorts[ks*20480 + col*32 + q2*8], q2=(q+((col&15)>>1))&3.
// ---------------------------------------------------------------------------
__global__ __launch_bounds__(256) void prep_weights(
    const float* __restrict__ WX, const float* __restrict__ V,
    const float* __restrict__ gate_w,
    short* __restrict__ Wt2, short* __restrict__ Vt) {
  __shared__ float lds[32 * 129];
  const int bid = blockIdx.x, t = threadIdx.x;

  if (bid < 128) {
    const int h = bid >> 4, ks = bid & 15;
    {
      const int kl = t >> 3, m8 = (t & 7) * 8;
      const float* src = WX + ((size_t)(h * DIM + ks * 32 + kl) * DM + m8);
      #pragma unroll
      for (int j = 0; j < 8; ++j) lds[kl * 129 + m8 + j] = src[j];
    }
    __syncthreads();
    {
      const int m = t >> 2, q = t & 3;
      const int col = h * 64 + m;
      const int q2 = (q + ((col & 15) >> 1)) & 3;
      short* dst = Wt2 + ks * 20480 + col * 32 + q2 * 8;
      #pragma unroll
      for (int j = 0; j < 8; ++j) dst[j] = f2b(lds[(q * 8 + j) * 129 + m]);
    }
  } else if (bid < 144) {
    const int ks = bid - 128;
    #pragma unroll
    for (int rep = 0; rep < 2; ++rep) {
      const int idx = rep * 2048 + t * 8;
      const int kl = idx >> 7, l8 = idx & 127;
      const float* src = gate_w + ((size_t)(ks * 32 + kl) * DL + l8);
      #pragma unroll
      for (int j = 0; j < 8; ++j) lds[kl * 129 + l8 + j] = src[j];
    }
    __syncthreads();
    #pragma unroll
    for (int rep = 0; rep < 2; ++rep) {
      const int piece = rep * 256 + t;
      const int l = piece >> 2, q = piece & 3;
      const int col = 512 + l;
      const int q2 = (q + ((col & 15) >> 1)) & 3;
      short* dst = Wt2 + ks * 20480 + col * 32 + q2 * 8;
      #pragma unroll
      for (int j = 0; j < 8; ++j) dst[j] = f2b(lds[(q * 8 + j) * 129 + l]);
    }
  } else {
    for (int r = 0; r < 32; ++r) {
      int i = t + r * 256;
      int l = i >> 6, m = i & 63;
      Vt[(size_t)l * DM + m] = f2b(V[(size_t)m * DL + l]);
    }
  }
}

// ---------------------------------------------------------------------------
// Kernel 2: fused projection GEMM  C[32768 x 640] = x[32768 x 512] * Wcat
// BM=64, 1024 thr = 16 waves (2 row x 8 col), wave tile 32x80, acc[2][5].
// B: LDS double-buffer via global_load_lds (each wave owns 2-3 of 40 1-KB
// units) with COUNTED vmcnt + raw s_barrier (T4) — no full drains.
// A: staged incrementally (slab ks+2 written during step ks from a load
// issued at step ks-1 — T14 issue-early/write-late). 2 barriers/step.
// LDS 144 KB -> 1 block/CU, grid 512, 2 rounds.
// ---------------------------------------------------------------------------
__global__ __launch_bounds__(1024, 4) void proj_kernel(
    const float* __restrict__ x, const short* __restrict__ Wt2,
    short* __restrict__ mh, short* __restrict__ gate_t) {
  __shared__ alignas(1024) short lds_b[2][20480];  // 2 x 40 KB B slabs (swizzled)
  __shared__ alignas(16)   short lds_a[32768];     // 64 KB: 16 slabs [64r][32k] swz
  const int tid = threadIdx.x;
  const int bm0 = blockIdx.x * 64;
  const int lane = tid & 63;
  const int w = tid >> 6;            // wave 0..15
  const int wr = w >> 3;             // 0..1 -> rows [32wr, 32wr+32)
  const int wc = w & 7;              // 0..7 -> cols [80wc, 80wc+80)
  const int r = lane & 15;
  const int q = lane >> 4;           // 0..3
  const int swz16 = ((q + (r >> 1)) & 3) * 16;
  char* lda = reinterpret_cast<char*>(lds_a);
  char* ldb = reinterpret_cast<char*>(lds_b);

  // A staging assignment: thread covers 2 f32 (=4 B bf16) of one slab
  const int arow = tid >> 4, ap2 = tid & 15;
  const int aq4 = ap2 >> 2, ao = ap2 & 3;
  const int aslot = (aq4 + ((arow & 15) >> 1)) & 3;
  const float* axsrc = x + ((size_t)(bm0 + arow) << 9) + ap2 * 2;
  char* adst0 = lda + arow * 64 + aslot * 16 + ao * 4;

  auto loadA = [&](int s) -> float2 {
    return *reinterpret_cast<const float2*>(axsrc + s * 32);
  };
  auto writeA = [&](float2 v, int s) {
    unsigned pk = ((unsigned)(unsigned short)f2b(v.y) << 16) |
                  (unsigned)(unsigned short)f2b(v.x);
    *reinterpret_cast<unsigned*>(adst0 + s * 4096) = pk;
  };
  auto stageB = [&](int ks, int buf) {
    #pragma unroll
    for (int i = 0; i < 3; ++i) {
      const int unit = w + 16 * i;
      if (unit < 40) {
        const short* gsrc = Wt2 + ks * 20480 + unit * 512 + lane * 8;
        __builtin_amdgcn_global_load_lds(
            (const __attribute__((address_space(1))) void*)gsrc,
            (__attribute__((address_space(3))) void*)(ldb + buf * 40960 + unit * 1024),
            16, 0, 0);
      }
    }
  };

  f32x4 acc[2][5];
  #pragma unroll
  for (int rt = 0; rt < 2; ++rt)
    #pragma unroll
    for (int ct = 0; ct < 5; ++ct) acc[rt][ct] = f32x4{0.f, 0.f, 0.f, 0.f};

  // ---- prologue: direct-stage A slabs 0,1; issue A slab-2 load; B slab 0.
  writeA(loadA(0), 0);
  writeA(loadA(1), 1);
  float2 avP = loadA(2);
  stageB(0, 0);

  const int aoffr = (32 * wr + r) * 64 + swz16;

  #pragma unroll
  for (int ks = 0; ks < 16; ++ks) {
    const int cur = ks & 1;
    float2 avN;
    if (ks < 13) avN = loadA(ks + 3);          // issue-early (consumed next iter)
    if (ks < 15) stageB(ks + 1, cur ^ 1);      // DMA next B slab
    if (ks < 14) writeA(avP, ks + 2);          // write-late (load from last iter)

    // counted wait: own B(ks) units retired; newer ops stay in flight.
    if (ks < 13) {
      if (w < 8) asm volatile("s_waitcnt vmcnt(4) lgkmcnt(0)" ::: "memory");
      else       asm volatile("s_waitcnt vmcnt(3) lgkmcnt(0)" ::: "memory");
    } else if (ks < 15) {
      if (w < 8) asm volatile("s_waitcnt vmcnt(3) lgkmcnt(0)" ::: "memory");
      else       asm volatile("s_waitcnt vmcnt(2) lgkmcnt(0)" ::: "memory");
    } else {
      asm volatile("s_waitcnt vmcnt(0) lgkmcnt(0)" ::: "memory");
    }
    __builtin_amdgcn_sched_barrier(0);
    __builtin_amdgcn_s_barrier();              // buf cur fully staged (all waves)

    // compute: 2 A-frags + 5 B-frags, 10 MFMA
    bf16x8 af0 = *reinterpret_cast<const bf16x8*>(lda + ks * 4096 + aoffr);
    bf16x8 af1 = *reinterpret_cast<const bf16x8*>(lda + ks * 4096 + aoffr + 1024);
    #pragma unroll
    for (int ct = 0; ct < 5; ++ct) {
      bf16x8 bf = *reinterpret_cast<const bf16x8*>(
          ldb + cur * 40960 + (80 * wc + 16 * ct + r) * 64 + swz16);
      acc[0][ct] = mfma_bf16(af0, bf, acc[0][ct]);
      acc[1][ct] = mfma_bf16(af1, bf, acc[1][ct]);
    }
    __builtin_amdgcn_sched_barrier(0);
    __builtin_amdgcn_s_barrier();              // reads done before buf reused
    avP = avN;
  }

  // epilogue (unchanged from R10): D row = 32wr+16rt+4q+j, col = 80wc+16ct+r
  #pragma unroll
  for (int rt = 0; rt < 2; ++rt) {
    #pragma unroll
    for (int ct = 0; ct < 5; ++ct) {
      const int colbase = 80 * wc + 16 * ct;
      const int grow0 = bm0 + 32 * wr + 16 * rt + 4 * q;
      if (colbase < NHEAD * DM) {
        const int col = colbase + r;
        #pragma unroll
        for (int j = 0; j < 4; ++j)
          mh[((size_t)(col >> 6) * MTOT + grow0 + j) * DM + (col & 63)] =
              f2b(acc[rt][ct][j]);
      } else {
        const int l = colbase + r - NHEAD * DM;
        s16x4 gv;
        gv.x = f2b(fast_sigmoid(acc[rt][ct][0]));
        gv.y = f2b(fast_sigmoid(acc[rt][ct][1]));
        gv.z = f2b(fast_sigmoid(acc[rt][ct][2]));
        gv.w = f2b(fast_sigmoid(acc[rt][ct][3]));
        *reinterpret_cast<s16x4*>(gate_t + (size_t)l * MTOT + grow0) = gv;
      }
    }
  }
}

// ---------------------------------------------------------------------------
// Kernel 3: scores[h][row] = sum_l tanh((mh_h.V)[row][l]) * gate[row][l] * W[h][l]
// ---------------------------------------------------------------------------
__global__ __launch_bounds__(256) void score_kernel(
    const short* __restrict__ mh, const short* __restrict__ gate_t,
    const short* __restrict__ Vt, const float* __restrict__ W,
    float* __restrict__ scores) {
  const int tid = threadIdx.x;
  const int lane = tid & 63;
  const int wv = tid >> 6;         // 0..3
  const int r = lane & 15, q = lane >> 4;
  const int row0 = blockIdx.x * 64;

  #pragma unroll
  for (int hh = 0; hh < 2; ++hh) {
    const int h = wv * 2 + hh;
    float wc[8];
    #pragma unroll
    for (int ct = 0; ct < 8; ++ct) wc[ct] = W[(size_t)h * DL + 16 * ct + r];

    #pragma unroll
    for (int rt = 0; rt < 4; ++rt) {
      const short* ap = mh + ((size_t)h * MTOT + row0 + 16 * rt + r) * DM + q * 8;
      bf16x8 a0 = *reinterpret_cast<const bf16x8*>(ap);
      bf16x8 a1 = *reinterpret_cast<const bf16x8*>(ap + 32);
      float sc[4] = {0.f, 0.f, 0.f, 0.f};
      #pragma unroll
      for (int ct = 0; ct < 8; ++ct) {
        const short* bp = Vt + (size_t)(16 * ct + r) * DM + q * 8;
        bf16x8 b0 = *reinterpret_cast<const bf16x8*>(bp);
        bf16x8 b1 = *reinterpret_cast<const bf16x8*>(bp + 32);
        f32x4 t = f32x4{0.f, 0.f, 0.f, 0.f};
        t = mfma_bf16(a0, b0, t);
        t = mfma_bf16(a1, b1, t);
        s16x4 ga = *reinterpret_cast<const s16x4*>(
            gate_t + (size_t)(16 * ct + r) * MTOT + row0 + 16 * rt + 4 * q);
        #pragma unroll
        for (int j = 0; j < 4; ++j) {
          float g = b2f((j == 0) ? ga.x : (j == 1) ? ga.y : (j == 2) ? ga.z : ga.w);
          sc[j] += fast_tanh(t[j]) * g * wc[ct];
        }
      }
      #pragma unroll
      for (int j = 0; j < 4; ++j) {
        sc[j] += __shfl_xor(sc[j], 1);
        sc[j] += __shfl_xor(sc[j], 2);
        sc[j] += __shfl_xor(sc[j], 4);
        sc[j] += __shfl_xor(sc[j], 8);
      }
      if (r < 4) {
        float v = (r == 0) ? sc[0] : (r == 1) ? sc[1] : (r == 2) ? sc[2] : sc[3];
        scores[(size_t)h * MTOT + row0 + 16 * rt + 4 * q + r] = v;
      }
    }
  }
}

// ---------------------------------------------------------------------------
// Kernel 4: masked softmax over N per (h,b). soft=0 for n >= true_num[b].
// ---------------------------------------------------------------------------
__global__ __launch_bounds__(256) void softmax_kernel(
    const float* __restrict__ scores, const int* __restrict__ true_num,
    float* __restrict__ soft, float* __restrict__ out_soft) {
  const int h = blockIdx.x >> 3, b = blockIdx.x & 7;
  const int tid = threadIdx.x;
  const int tn = true_num[b];
  const float* s = scores + ((size_t)h * BBAG + b) * NINST;
  __shared__ float red[8];

  float vals[16];
  float mx = -3.0e38f;
  #pragma unroll
  for (int i = 0; i < 16; ++i) {
    int n = tid + i * 256;
    float v = s[n];
    vals[i] = (n < tn) ? v : -3.0e38f;
    mx = fmaxf(mx, vals[i]);
  }
  #pragma unroll
  for (int m = 1; m < 64; m <<= 1) mx = fmaxf(mx, __shfl_xor(mx, m));
  if ((tid & 63) == 0) red[tid >> 6] = mx;
  __syncthreads();
  mx = fmaxf(fmaxf(red[0], red[1]), fmaxf(red[2], red[3]));

  float sum = 0.f;
  #pragma unroll
  for (int i = 0; i < 16; ++i) {
    int n = tid + i * 256;
    float e = (n < tn) ? expf(vals[i] - mx) : 0.0f;
    vals[i] = e;
    sum += e;
  }
  #pragma unroll
  for (int m = 1; m < 64; m <<= 1) sum += __shfl_xor(sum, m);
  if ((tid & 63) == 0) red[4 + (tid >> 6)] = sum;
  __syncthreads();
  sum = red[4] + red[5] + red[6] + red[7];
  float inv = 1.0f / sum;

  float* so = soft + ((size_t)h * BBAG + b) * NINST;
  #pragma unroll
  for (int i = 0; i < 16; ++i) {
    int n = tid + i * 256;
    float v = vals[i] * inv;
    so[n] = v;
    if (h == 0) out_soft[(size_t)b * NINST + n] = v;
  }
}

// ---------------------------------------------------------------------------
// Kernel 5a: partial pooling. grid = (h,b,chunk): 8*8*8 = 512 blocks.
// ---------------------------------------------------------------------------
__global__ __launch_bounds__(256) void pool_partial(
    const short* __restrict__ mh, const float* __restrict__ soft,
    float* __restrict__ part) {
  const int c = blockIdx.x & (NCHUNK - 1);
  const int hb = blockIdx.x / NCHUNK;        // h*8 + b
  const int h = hb >> 3, b = hb & 7;
  const int tid = threadIdx.x;
  const int m = tid & 63, g = tid >> 6;
  const int n0 = c * (NINST / NCHUNK);
  const float* so = soft + ((size_t)h * BBAG + b) * NINST;
  const short* mp = mh + ((size_t)h * MTOT + (size_t)b * NINST) * DM;
  float acc = 0.f;
  #pragma unroll 4
  for (int n = n0 + g; n < n0 + NINST / NCHUNK; n += 4) {
    acc += so[n] * b2f(mp[(size_t)n * DM + m]);
  }
  __shared__ float red[256];
  red[tid] = acc;
  __syncthreads();
  if (tid < 64) {
    part[(size_t)(hb * NCHUNK + c) * DM + tid] =
        red[tid] + red[tid + 64] + red[tid + 128] + red[tid + 192];
  }
}

// ---------------------------------------------------------------------------
// Kernel 5b: reduce partials -> feat[b][h*64+m]
// ---------------------------------------------------------------------------
__global__ __launch_bounds__(256) void pool_reduce(
    const float* __restrict__ part, float* __restrict__ out_feat) {
  int g = blockIdx.x * blockDim.x + threadIdx.x;   // 4096 outputs
  int hb = g >> 6, m = g & 63;
  int h = hb >> 3, b = hb & 7;
  float s = 0.f;
  #pragma unroll
  for (int c = 0; c < NCHUNK; ++c)
    s += part[(size_t)(hb * NCHUNK + c) * DM + m];
  out_feat[(size_t)b * (NHEAD * DM) + h * DM + m] = s;
}

// ---------------------------------------------------------------------------
extern "C" void kernel_launch(void* const* d_in, const int* in_sizes, int n_in,
                              void* d_out, int out_size, void* d_ws, size_t ws_size,
                              hipStream_t stream) {
  (void)in_sizes; (void)n_in; (void)out_size; (void)ws_size;
  const float* x      = (const float*)d_in[0];
  const float* WX     = (const float*)d_in[1];
  const float* V      = (const float*)d_in[2];
  const float* W      = (const float*)d_in[3];
  const float* gate_w = (const float*)d_in[4];
  const int* true_num = (const int*)d_in[5];
  float* out = (float*)d_out;

  char* ws = (char*)d_ws;
  short* Wt2    = (short*)ws;  ws += (size_t)NCOL * DIM * 2;            //    655,360 B
  short* Vt     = (short*)ws;  ws += (size_t)DL * DM * 2;               //     16,384 B
  short* mh     = (short*)ws;  ws += (size_t)NHEAD * MTOT * DM * 2;     // 33,554,432 B
  short* gate_t = (short*)ws;  ws += (size_t)DL * MTOT * 2;             //  8,388,608 B
  float* scores = (float*)ws;  ws += (size_t)NHEAD * MTOT * 4;          //  1,048,576 B
  float* soft   = (float*)ws;  ws += (size_t)NHEAD * MTOT * 4;          //  1,048,576 B
  float* part   = (float*)ws;  ws += (size_t)NHEAD * BBAG * NCHUNK * DM * 4; // 131,072 B

  prep_weights<<<dim3(145), dim3(256), 0, stream>>>(WX, V, gate_w, Wt2, Vt);
  proj_kernel<<<dim3(MTOT / 64), dim3(1024), 0, stream>>>(x, Wt2, mh, gate_t);
  score_kernel<<<dim3(MTOT / 64), dim3(256), 0, stream>>>(mh, gate_t, Vt, W, scores);
  softmax_kernel<<<dim3(NHEAD * BBAG), dim3(256), 0, stream>>>(
      scores, true_num, soft, out + BBAG * NHEAD * DM);
  pool_partial<<<dim3(NHEAD * BBAG * NCHUNK), dim3(256), 0, stream>>>(mh, soft, part);
  pool_reduce<<<dim3(NHEAD * BBAG * DM / 256), dim3(256), 0, stream>>>(part, out);
}

// Round 12
// 101.740 us; speedup vs baseline: 1.4616x; 1.0136x over previous
//
#include <hip/hip_runtime.h>
#include <hip/hip_bf16.h>

#define DIM   512
#define NHEAD 8
#define DM    64
#define DL    128
#define BBAG  8
#define NINST 4096
#define MTOT  (BBAG*NINST)     // 32768 instances
#define NCOL  (NHEAD*DM + DL)  // 640 fused output columns (8*64 mh + 128 gate)
#define NCHUNK 16              // pool n-chunks per (h,b)

typedef short   bf16x8 __attribute__((ext_vector_type(8)));
typedef __bf16  bf16v8 __attribute__((ext_vector_type(8)));
typedef float   f32x4  __attribute__((ext_vector_type(4)));
typedef short   s16x4  __attribute__((ext_vector_type(4)));

__device__ __forceinline__ short f2b(float f) {
  __hip_bfloat16 h = __float2bfloat16(f);
  return __builtin_bit_cast(short, h);
}
__device__ __forceinline__ float b2f(short s) {
  __hip_bfloat16 h = __builtin_bit_cast(__hip_bfloat16, s);
  return __bfloat162float(h);
}
__device__ __forceinline__ f32x4 mfma_bf16(bf16x8 a, bf16x8 b, f32x4 c) {
  return __builtin_amdgcn_mfma_f32_16x16x32_bf16(
      __builtin_bit_cast(bf16v8, a), __builtin_bit_cast(bf16v8, b), c, 0, 0, 0);
}
__device__ __forceinline__ float fast_tanh(float x) {
  float t = __expf(2.0f * x);
  return 1.0f - 2.0f * __builtin_amdgcn_rcpf(t + 1.0f);
}
__device__ __forceinline__ float fast_sigmoid(float x) {
  return __builtin_amdgcn_rcpf(1.0f + __expf(-x));
}

// ---------------------------------------------------------------------------
// Kernel 1: build Wt2/Vt with coalesced LDS-transpose (R9, validated).
// Wt2: shorts[ks*20480 + col*32 + q2*8], q2=(q+((col&15)>>1))&3.
// ---------------------------------------------------------------------------
__global__ __launch_bounds__(256) void prep_weights(
    const float* __restrict__ WX, const float* __restrict__ V,
    const float* __restrict__ gate_w,
    short* __restrict__ Wt2, short* __restrict__ Vt) {
  __shared__ float lds[32 * 129];
  const int bid = blockIdx.x, t = threadIdx.x;

  if (bid < 128) {
    const int h = bid >> 4, ks = bid & 15;
    {
      const int kl = t >> 3, m8 = (t & 7) * 8;
      const float* src = WX + ((size_t)(h * DIM + ks * 32 + kl) * DM + m8);
      #pragma unroll
      for (int j = 0; j < 8; ++j) lds[kl * 129 + m8 + j] = src[j];
    }
    __syncthreads();
    {
      const int m = t >> 2, q = t & 3;
      const int col = h * 64 + m;
      const int q2 = (q + ((col & 15) >> 1)) & 3;
      short* dst = Wt2 + ks * 20480 + col * 32 + q2 * 8;
      #pragma unroll
      for (int j = 0; j < 8; ++j) dst[j] = f2b(lds[(q * 8 + j) * 129 + m]);
    }
  } else if (bid < 144) {
    const int ks = bid - 128;
    #pragma unroll
    for (int rep = 0; rep < 2; ++rep) {
      const int idx = rep * 2048 + t * 8;
      const int kl = idx >> 7, l8 = idx & 127;
      const float* src = gate_w + ((size_t)(ks * 32 + kl) * DL + l8);
      #pragma unroll
      for (int j = 0; j < 8; ++j) lds[kl * 129 + l8 + j] = src[j];
    }
    __syncthreads();
    #pragma unroll
    for (int rep = 0; rep < 2; ++rep) {
      const int piece = rep * 256 + t;
      const int l = piece >> 2, q = piece & 3;
      const int col = 512 + l;
      const int q2 = (q + ((col & 15) >> 1)) & 3;
      short* dst = Wt2 + ks * 20480 + col * 32 + q2 * 8;
      #pragma unroll
      for (int j = 0; j < 8; ++j) dst[j] = f2b(lds[(q * 8 + j) * 129 + l]);
    }
  } else {
    for (int r = 0; r < 32; ++r) {
      int i = t + r * 256;
      int l = i >> 6, m = i & 63;
      Vt[(size_t)l * DM + m] = f2b(V[(size_t)m * DL + l]);
    }
  }
}

// ---------------------------------------------------------------------------
// Kernel 2: fused projection GEMM  C[32768 x 640] = x[32768 x 512] * Wcat
// BM=128, grid=256 (1 block/CU, ONE round). 1024 thr = 16 waves (2 row x
// 8 col), wave tile 64x80, acc[4][5]. B: shared LDS dbuf via global_load_lds
// (40 x 1KB units/step, counted vmcnt, 2 s_barrier/step). A: 4-slab rolling
// LDS buffer, T14 issue-early/write-late. LDS 112 KB. B L2-traffic per row
// HALVED vs BM=64 (the R10/R11 invariant cost).
// ---------------------------------------------------------------------------
__global__ __launch_bounds__(1024) void proj_kernel(
    const float* __restrict__ x, const short* __restrict__ Wt2,
    short* __restrict__ mh, short* __restrict__ gate_t) {
  __shared__ alignas(1024) short lds_b[2][20480];  // 2 x 40 KB B slabs (swizzled)
  __shared__ alignas(16)   short lds_a[4][4096];   // 4 x 8 KB A slabs (rolling)
  const int tid = threadIdx.x;
  const int bm0 = blockIdx.x * 128;
  const int lane = tid & 63;
  const int w = tid >> 6;            // wave 0..15
  const int wr = w >> 3;             // 0..1 -> rows [64wr, 64wr+64)
  const int wc = w & 7;              // 0..7 -> cols [80wc, 80wc+80)
  const int r = lane & 15;
  const int q = lane >> 4;           // 0..3
  const int swz16 = ((q + (r >> 1)) & 3) * 16;
  char* lda = reinterpret_cast<char*>(lds_a);
  char* ldb = reinterpret_cast<char*>(lds_b);
  const int nunits = (w < 8) ? 3 : 2;   // B units owned: w, w+16, (w+32<40)

  // A staging: thread = (row 0..127, piece p 0..7); 16B f32 -> 8B bf16
  const int arow = tid >> 3, ap = tid & 7;
  const int aslot = ((ap >> 1) + ((arow & 15) >> 1)) & 3;
  const float* axsrc = x + ((size_t)(bm0 + arow) << 9) + (ap << 2);
  char* adst0 = lda + arow * 64 + aslot * 16 + (ap & 1) * 8;

  auto loadA = [&](int s) -> f32x4 {
    return *reinterpret_cast<const f32x4*>(axsrc + s * 32);
  };
  auto writeA = [&](f32x4 v, int s) {
    s16x4 sv; sv.x = f2b(v[0]); sv.y = f2b(v[1]); sv.z = f2b(v[2]); sv.w = f2b(v[3]);
    *reinterpret_cast<s16x4*>(adst0 + (s & 3) * 8192) = sv;
  };
  auto stageB = [&](int ks, int buf) {
    #pragma unroll
    for (int i = 0; i < 3; ++i) {
      const int unit = w + 16 * i;
      if (unit < 40) {
        const short* gsrc = Wt2 + ks * 20480 + unit * 512 + lane * 8;
        __builtin_amdgcn_global_load_lds(
            (const __attribute__((address_space(1))) void*)gsrc,
            (__attribute__((address_space(3))) void*)(ldb + buf * 40960 + unit * 1024),
            16, 0, 0);
      }
    }
  };

  f32x4 acc[4][5];
  #pragma unroll
  for (int rt = 0; rt < 4; ++rt)
    #pragma unroll
    for (int ct = 0; ct < 5; ++ct) acc[rt][ct] = f32x4{0.f, 0.f, 0.f, 0.f};

  // ---- prologue: A slabs 0,1 staged; A(2) in regs; B slab 0 DMA.
  writeA(loadA(0), 0);
  writeA(loadA(1), 1);
  f32x4 avP = loadA(2);
  stageB(0, 0);

  const int aoffr = (64 * wr + r) * 64 + swz16;   // + 16rt*64 per frag

  #pragma unroll
  for (int ks = 0; ks < 16; ++ks) {
    const int cur = ks & 1;
    f32x4 avN;
    if (ks < 13) avN = loadA(ks + 3);          // issue-early
    if (ks < 14) writeA(avP, ks + 2);          // write-late (slab (ks+2)&3)
    if (ks < 15) stageB(ks + 1, cur ^ 1);      // DMA next B slab

    // counted wait: retire own B(ks) units; keep newer ops in flight.
    if (ks < 13) {
      if (w < 8) asm volatile("s_waitcnt vmcnt(4) lgkmcnt(0)" ::: "memory");
      else       asm volatile("s_waitcnt vmcnt(3) lgkmcnt(0)" ::: "memory");
    } else if (ks < 15) {
      if (w < 8) asm volatile("s_waitcnt vmcnt(3) lgkmcnt(0)" ::: "memory");
      else       asm volatile("s_waitcnt vmcnt(2) lgkmcnt(0)" ::: "memory");
    } else {
      asm volatile("s_waitcnt vmcnt(0) lgkmcnt(0)" ::: "memory");
    }
    __builtin_amdgcn_sched_barrier(0);
    __builtin_amdgcn_s_barrier();              // buf cur fully staged

    bf16x8 af[4];
    #pragma unroll
    for (int rt = 0; rt < 4; ++rt)
      af[rt] = *reinterpret_cast<const bf16x8*>(
          lda + (ks & 3) * 8192 + aoffr + rt * 1024);
    #pragma unroll
    for (int ct = 0; ct < 5; ++ct) {
      bf16x8 bf = *reinterpret_cast<const bf16x8*>(
          ldb + cur * 40960 + (80 * wc + 16 * ct + r) * 64 + swz16);
      #pragma unroll
      for (int rt = 0; rt < 4; ++rt)
        acc[rt][ct] = mfma_bf16(af[rt], bf, acc[rt][ct]);
    }
    __builtin_amdgcn_sched_barrier(0);
    __builtin_amdgcn_s_barrier();              // reads done before buf reuse
    avP = avN;
  }

  // epilogue: D row = 64wr+16rt+4q+j, col = 80wc+16ct+r
  #pragma unroll
  for (int rt = 0; rt < 4; ++rt) {
    #pragma unroll
    for (int ct = 0; ct < 5; ++ct) {
      const int colbase = 80 * wc + 16 * ct;
      const int grow0 = bm0 + 64 * wr + 16 * rt + 4 * q;
      if (colbase < NHEAD * DM) {
        const int col = colbase + r;
        #pragma unroll
        for (int j = 0; j < 4; ++j)
          mh[((size_t)(col >> 6) * MTOT + grow0 + j) * DM + (col & 63)] =
              f2b(acc[rt][ct][j]);
      } else {
        const int l = colbase + r - NHEAD * DM;
        s16x4 gv;
        gv.x = f2b(fast_sigmoid(acc[rt][ct][0]));
        gv.y = f2b(fast_sigmoid(acc[rt][ct][1]));
        gv.z = f2b(fast_sigmoid(acc[rt][ct][2]));
        gv.w = f2b(fast_sigmoid(acc[rt][ct][3]));
        *reinterpret_cast<s16x4*>(gate_t + (size_t)l * MTOT + grow0) = gv;
      }
    }
  }
}

// ---------------------------------------------------------------------------
// Kernel 3: scores[h][row] = sum_l tanh((mh_h.V)[row][l]) * gate[row][l] * W[h][l]
// ---------------------------------------------------------------------------
__global__ __launch_bounds__(256) void score_kernel(
    const short* __restrict__ mh, const short* __restrict__ gate_t,
    const short* __restrict__ Vt, const float* __restrict__ W,
    float* __restrict__ scores) {
  const int tid = threadIdx.x;
  const int lane = tid & 63;
  const int wv = tid >> 6;         // 0..3
  const int r = lane & 15, q = lane >> 4;
  const int row0 = blockIdx.x * 64;

  #pragma unroll
  for (int hh = 0; hh < 2; ++hh) {
    const int h = wv * 2 + hh;
    float wc[8];
    #pragma unroll
    for (int ct = 0; ct < 8; ++ct) wc[ct] = W[(size_t)h * DL + 16 * ct + r];

    #pragma unroll
    for (int rt = 0; rt < 4; ++rt) {
      const short* ap = mh + ((size_t)h * MTOT + row0 + 16 * rt + r) * DM + q * 8;
      bf16x8 a0 = *reinterpret_cast<const bf16x8*>(ap);
      bf16x8 a1 = *reinterpret_cast<const bf16x8*>(ap + 32);
      float sc[4] = {0.f, 0.f, 0.f, 0.f};
      #pragma unroll
      for (int ct = 0; ct < 8; ++ct) {
        const short* bp = Vt + (size_t)(16 * ct + r) * DM + q * 8;
        bf16x8 b0 = *reinterpret_cast<const bf16x8*>(bp);
        bf16x8 b1 = *reinterpret_cast<const bf16x8*>(bp + 32);
        f32x4 t = f32x4{0.f, 0.f, 0.f, 0.f};
        t = mfma_bf16(a0, b0, t);
        t = mfma_bf16(a1, b1, t);
        s16x4 ga = *reinterpret_cast<const s16x4*>(
            gate_t + (size_t)(16 * ct + r) * MTOT + row0 + 16 * rt + 4 * q);
        #pragma unroll
        for (int j = 0; j < 4; ++j) {
          float g = b2f((j == 0) ? ga.x : (j == 1) ? ga.y : (j == 2) ? ga.z : ga.w);
          sc[j] += fast_tanh(t[j]) * g * wc[ct];
        }
      }
      #pragma unroll
      for (int j = 0; j < 4; ++j) {
        sc[j] += __shfl_xor(sc[j], 1);
        sc[j] += __shfl_xor(sc[j], 2);
        sc[j] += __shfl_xor(sc[j], 4);
        sc[j] += __shfl_xor(sc[j], 8);
      }
      if (r < 4) {
        float v = (r == 0) ? sc[0] : (r == 1) ? sc[1] : (r == 2) ? sc[2] : sc[3];
        scores[(size_t)h * MTOT + row0 + 16 * rt + 4 * q + r] = v;
      }
    }
  }
}

// ---------------------------------------------------------------------------
// Kernel 4: masked softmax over N per (h,b). soft=0 for n >= true_num[b].
// ---------------------------------------------------------------------------
__global__ __launch_bounds__(256) void softmax_kernel(
    const float* __restrict__ scores, const int* __restrict__ true_num,
    float* __restrict__ soft, float* __restrict__ out_soft) {
  const int h = blockIdx.x >> 3, b = blockIdx.x & 7;
  const int tid = threadIdx.x;
  const int tn = true_num[b];
  const float* s = scores + ((size_t)h * BBAG + b) * NINST;
  __shared__ float red[8];

  float vals[16];
  float mx = -3.0e38f;
  #pragma unroll
  for (int i = 0; i < 16; ++i) {
    int n = tid + i * 256;
    float v = s[n];
    vals[i] = (n < tn) ? v : -3.0e38f;
    mx = fmaxf(mx, vals[i]);
  }
  #pragma unroll
  for (int m = 1; m < 64; m <<= 1) mx = fmaxf(mx, __shfl_xor(mx, m));
  if ((tid & 63) == 0) red[tid >> 6] = mx;
  __syncthreads();
  mx = fmaxf(fmaxf(red[0], red[1]), fmaxf(red[2], red[3]));

  float sum = 0.f;
  #pragma unroll
  for (int i = 0; i < 16; ++i) {
    int n = tid + i * 256;
    float e = (n < tn) ? expf(vals[i] - mx) : 0.0f;
    vals[i] = e;
    sum += e;
  }
  #pragma unroll
  for (int m = 1; m < 64; m <<= 1) sum += __shfl_xor(sum, m);
  if ((tid & 63) == 0) red[4 + (tid >> 6)] = sum;
  __syncthreads();
  sum = red[4] + red[5] + red[6] + red[7];
  float inv = 1.0f / sum;

  float* so = soft + ((size_t)h * BBAG + b) * NINST;
  #pragma unroll
  for (int i = 0; i < 16; ++i) {
    int n = tid + i * 256;
    float v = vals[i] * inv;
    so[n] = v;
    if (h == 0) out_soft[(size_t)b * NINST + n] = v;
  }
}

// ---------------------------------------------------------------------------
// Kernel 5a: partial pooling. grid = (h,b,chunk): 8*8*16 = 1024 blocks.
// ---------------------------------------------------------------------------
__global__ __launch_bounds__(256) void pool_partial(
    const short* __restrict__ mh, const float* __restrict__ soft,
    float* __restrict__ part) {
  const int c = blockIdx.x & (NCHUNK - 1);
  const int hb = blockIdx.x / NCHUNK;        // h*8 + b
  const int h = hb >> 3, b = hb & 7;
  const int tid = threadIdx.x;
  const int m = tid & 63, g = tid >> 6;
  const int n0 = c * (NINST / NCHUNK);
  const float* so = soft + ((size_t)h * BBAG + b) * NINST;
  const short* mp = mh + ((size_t)h * MTOT + (size_t)b * NINST) * DM;
  float acc = 0.f;
  #pragma unroll 4
  for (int n = n0 + g; n < n0 + NINST / NCHUNK; n += 4) {
    acc += so[n] * b2f(mp[(size_t)n * DM + m]);
  }
  __shared__ float red[256];
  red[tid] = acc;
  __syncthreads();
  if (tid < 64) {
    part[(size_t)(hb * NCHUNK + c) * DM + tid] =
        red[tid] + red[tid + 64] + red[tid + 128] + red[tid + 192];
  }
}

// ---------------------------------------------------------------------------
// Kernel 5b: reduce partials -> feat[b][h*64+m]
// ---------------------------------------------------------------------------
__global__ __launch_bounds__(256) void pool_reduce(
    const float* __restrict__ part, float* __restrict__ out_feat) {
  int g = blockIdx.x * blockDim.x + threadIdx.x;   // 4096 outputs
  int hb = g >> 6, m = g & 63;
  int h = hb >> 3, b = hb & 7;
  float s = 0.f;
  #pragma unroll
  for (int c = 0; c < NCHUNK; ++c)
    s += part[(size_t)(hb * NCHUNK + c) * DM + m];
  out_feat[(size_t)b * (NHEAD * DM) + h * DM + m] = s;
}

// ---------------------------------------------------------------------------
extern "C" void kernel_launch(void* const* d_in, const int* in_sizes, int n_in,
                              void* d_out, int out_size, void* d_ws, size_t ws_size,
                              hipStream_t stream) {
  (void)in_sizes; (void)n_in; (void)out_size; (void)ws_size;
  const float* x      = (const float*)d_in[0];
  const float* WX     = (const float*)d_in[1];
  const float* V      = (const float*)d_in[2];
  const float* W      = (const float*)d_in[3];
  const float* gate_w = (const float*)d_in[4];
  const int* true_num = (const int*)d_in[5];
  float* out = (float*)d_out;

  char* ws = (char*)d_ws;
  short* Wt2    = (short*)ws;  ws += (size_t)NCOL * DIM * 2;            //    655,360 B
  short* Vt     = (short*)ws;  ws += (size_t)DL * DM * 2;               //     16,384 B
  short* mh     = (short*)ws;  ws += (size_t)NHEAD * MTOT * DM * 2;     // 33,554,432 B
  short* gate_t = (short*)ws;  ws += (size_t)DL * MTOT * 2;             //  8,388,608 B
  float* scores = (float*)ws;  ws += (size_t)NHEAD * MTOT * 4;          //  1,048,576 B
  float* soft   = (float*)ws;  ws += (size_t)NHEAD * MTOT * 4;          //  1,048,576 B
  float* part   = (float*)ws;  ws += (size_t)NHEAD * BBAG * NCHUNK * DM * 4; // 524,288 B

  prep_weights<<<dim3(145), dim3(256), 0, stream>>>(WX, V, gate_w, Wt2, Vt);
  proj_kernel<<<dim3(MTOT / 128), dim3(1024), 0, stream>>>(x, Wt2, mh, gate_t);
  score_kernel<<<dim3(MTOT / 64), dim3(256), 0, stream>>>(mh, gate_t, Vt, W, scores);
  softmax_kernel<<<dim3(NHEAD * BBAG), dim3(256), 0, stream>>>(
      scores, true_num, soft, out + BBAG * NHEAD * DM);
  pool_partial<<<dim3(NHEAD * BBAG * NCHUNK), dim3(256), 0, stream>>>(mh, soft, part);
  pool_reduce<<<dim3(NHEAD * BBAG * DM / 256), dim3(256), 0, stream>>>(part, out);
}

// Round 13
// 99.216 us; speedup vs baseline: 1.4988x; 1.0254x over previous
//
#include <hip/hip_runtime.h>
#include <hip/hip_bf16.h>

#define DIM   512
#define NHEAD 8
#define DM    64
#define DL    128
#define BBAG  8
#define NINST 4096
#define MTOT  (BBAG*NINST)     // 32768 instances
#define NCOL  (NHEAD*DM + DL)  // 640 fused output columns (8*64 mh + 128 gate)
#define NCHUNK 16              // pool n-chunks per (h,b)

typedef short   bf16x8 __attribute__((ext_vector_type(8)));
typedef __bf16  bf16v8 __attribute__((ext_vector_type(8)));
typedef float   f32x4  __attribute__((ext_vector_type(4)));
typedef short   s16x4  __attribute__((ext_vector_type(4)));

__device__ __forceinline__ short f2b(float f) {
  __hip_bfloat16 h = __float2bfloat16(f);
  return __builtin_bit_cast(short, h);
}
__device__ __forceinline__ float b2f(short s) {
  __hip_bfloat16 h = __builtin_bit_cast(__hip_bfloat16, s);
  return __bfloat162float(h);
}
__device__ __forceinline__ f32x4 mfma_bf16(bf16x8 a, bf16x8 b, f32x4 c) {
  return __builtin_amdgcn_mfma_f32_16x16x32_bf16(
      __builtin_bit_cast(bf16v8, a), __builtin_bit_cast(bf16v8, b), c, 0, 0, 0);
}
__device__ __forceinline__ float fast_tanh(float x) {
  float t = __expf(2.0f * x);
  return 1.0f - 2.0f * __builtin_amdgcn_rcpf(t + 1.0f);
}
__device__ __forceinline__ float fast_sigmoid(float x) {
  return __builtin_amdgcn_rcpf(1.0f + __expf(-x));
}

// ---------------------------------------------------------------------------
// Kernel 1: build Wt2/Vt with coalesced LDS-transpose (R9, validated).
// Wt2: shorts[ks*20480 + col*32 + q2*8], q2=(q+((col&15)>>1))&3.
// ---------------------------------------------------------------------------
__global__ __launch_bounds__(256) void prep_weights(
    const float* __restrict__ WX, const float* __restrict__ V,
    const float* __restrict__ gate_w,
    short* __restrict__ Wt2, short* __restrict__ Vt) {
  __shared__ float lds[32 * 129];
  const int bid = blockIdx.x, t = threadIdx.x;

  if (bid < 128) {
    const int h = bid >> 4, ks = bid & 15;
    {
      const int kl = t >> 3, m8 = (t & 7) * 8;
      const float* src = WX + ((size_t)(h * DIM + ks * 32 + kl) * DM + m8);
      #pragma unroll
      for (int j = 0; j < 8; ++j) lds[kl * 129 + m8 + j] = src[j];
    }
    __syncthreads();
    {
      const int m = t >> 2, q = t & 3;
      const int col = h * 64 + m;
      const int q2 = (q + ((col & 15) >> 1)) & 3;
      short* dst = Wt2 + ks * 20480 + col * 32 + q2 * 8;
      #pragma unroll
      for (int j = 0; j < 8; ++j) dst[j] = f2b(lds[(q * 8 + j) * 129 + m]);
    }
  } else if (bid < 144) {
    const int ks = bid - 128;
    #pragma unroll
    for (int rep = 0; rep < 2; ++rep) {
      const int idx = rep * 2048 + t * 8;
      const int kl = idx >> 7, l8 = idx & 127;
      const float* src = gate_w + ((size_t)(ks * 32 + kl) * DL + l8);
      #pragma unroll
      for (int j = 0; j < 8; ++j) lds[kl * 129 + l8 + j] = src[j];
    }
    __syncthreads();
    #pragma unroll
    for (int rep = 0; rep < 2; ++rep) {
      const int piece = rep * 256 + t;
      const int l = piece >> 2, q = piece & 3;
      const int col = 512 + l;
      const int q2 = (q + ((col & 15) >> 1)) & 3;
      short* dst = Wt2 + ks * 20480 + col * 32 + q2 * 8;
      #pragma unroll
      for (int j = 0; j < 8; ++j) dst[j] = f2b(lds[(q * 8 + j) * 129 + l]);
    }
  } else {
    for (int r = 0; r < 32; ++r) {
      int i = t + r * 256;
      int l = i >> 6, m = i & 63;
      Vt[(size_t)l * DM + m] = f2b(V[(size_t)m * DL + l]);
    }
  }
}

// ---------------------------------------------------------------------------
// Kernel 2: fused projection GEMM  C[32768 x 640] = x[32768 x 512] * Wcat
// BM=64, 512 thr = 8 waves as 1x8: wave = ALL 64 rows x 80 cols, acc[4][5].
// KEY: no B duplication across waves (each of the 640 cols loaded by exactly
// one wave) -> block traffic 0.87 MB vs R10's 1.52 MB (2x-dup B was the
// per-CU vmem wall). A staged once in 64 KB LDS (swizzled); B global->reg
// with unrolled depth-2 pipeline; zero barriers in K-loop.
// ---------------------------------------------------------------------------
__global__ __launch_bounds__(512) void proj_kernel(
    const float* __restrict__ x, const short* __restrict__ Wt2,
    short* __restrict__ mh, short* __restrict__ gate_t) {
  __shared__ alignas(16) short lds_a[32768];   // 64 KB: 16 slabs [64r][32k] swz
  const int tid = threadIdx.x;
  const int bm0 = blockIdx.x * 64;
  const int lane = tid & 63;
  const int w = tid >> 6;            // wave 0..7 -> cols [80w, 80w+80)
  const int r = lane & 15;
  const int q = lane >> 4;           // 0..3
  const int swzs = (q + (r >> 1)) & 3;
  char* lda = reinterpret_cast<char*>(lds_a);

  // ---- prologue: stage A tile (64 rows x 512 k) f32 -> bf16 LDS, swizzled.
  {
    const int arow = tid >> 3, ap = tid & 7;
    const int aslot = ((ap >> 1) + ((arow & 15) >> 1)) & 3;
    const float* asrc = x + ((size_t)(bm0 + arow) << 9) + (ap << 2);
    char* adst = lda + arow * 64 + aslot * 16 + (ap & 1) * 8;
    #pragma unroll
    for (int ks = 0; ks < 16; ++ks) {
      f32x4 v = *reinterpret_cast<const f32x4*>(asrc + ks * 32);
      s16x4 sv; sv.x = f2b(v[0]); sv.y = f2b(v[1]); sv.z = f2b(v[2]); sv.w = f2b(v[3]);
      *reinterpret_cast<s16x4*>(adst + ks * 4096) = sv;
    }
  }

  const short* bbase = Wt2 + (80 * w + r) * 32 + swzs * 8;
  auto loadB = [&](int ks, bf16x8 bf[5]) {
    const short* p = bbase + ks * 20480;
    #pragma unroll
    for (int ct = 0; ct < 5; ++ct)
      bf[ct] = *reinterpret_cast<const bf16x8*>(p + ct * 512);
  };

  bf16x8 bufs[3][5];     // B triple buffer (static idx after unroll)
  bf16x8 afb[2][4];      // A-frag double buffer

  // B prefetch for ks=0,1 (global->reg, independent of LDS barrier)
  loadB(0, bufs[0]);
  loadB(1, bufs[1]);

  __syncthreads();

  const int aoff = r * 64 + swzs * 16;
  #pragma unroll
  for (int rt = 0; rt < 4; ++rt)
    afb[0][rt] = *reinterpret_cast<const bf16x8*>(lda + 0 * 4096 + aoff + rt * 1024);

  f32x4 acc[4][5];
  #pragma unroll
  for (int rt = 0; rt < 4; ++rt)
    #pragma unroll
    for (int ct = 0; ct < 5; ++ct) acc[rt][ct] = f32x4{0.f, 0.f, 0.f, 0.f};

  #pragma unroll
  for (int ks = 0; ks < 16; ++ks) {
    if (ks + 2 < 16) loadB(ks + 2, bufs[(ks + 2) % 3]);
    if (ks + 1 < 16) {
      #pragma unroll
      for (int rt = 0; rt < 4; ++rt)
        afb[(ks + 1) & 1][rt] = *reinterpret_cast<const bf16x8*>(
            lda + (ks + 1) * 4096 + aoff + rt * 1024);
    }
    #pragma unroll
    for (int ct = 0; ct < 5; ++ct)
      #pragma unroll
      for (int rt = 0; rt < 4; ++rt)
        acc[rt][ct] = mfma_bf16(afb[ks & 1][rt], bufs[ks % 3][ct], acc[rt][ct]);
  }

  // epilogue: D row = 16rt+4q+j, col = 80w+16ct+r
  #pragma unroll
  for (int rt = 0; rt < 4; ++rt) {
    #pragma unroll
    for (int ct = 0; ct < 5; ++ct) {
      const int colbase = 80 * w + 16 * ct;
      const int grow0 = bm0 + 16 * rt + 4 * q;
      if (colbase < NHEAD * DM) {
        const int col = colbase + r;
        #pragma unroll
        for (int j = 0; j < 4; ++j)
          mh[((size_t)(col >> 6) * MTOT + grow0 + j) * DM + (col & 63)] =
              f2b(acc[rt][ct][j]);
      } else {
        const int l = colbase + r - NHEAD * DM;
        s16x4 gv;
        gv.x = f2b(fast_sigmoid(acc[rt][ct][0]));
        gv.y = f2b(fast_sigmoid(acc[rt][ct][1]));
        gv.z = f2b(fast_sigmoid(acc[rt][ct][2]));
        gv.w = f2b(fast_sigmoid(acc[rt][ct][3]));
        *reinterpret_cast<s16x4*>(gate_t + (size_t)l * MTOT + grow0) = gv;
      }
    }
  }
}

// ---------------------------------------------------------------------------
// Kernel 3: scores[h][row] = sum_l tanh((mh_h.V)[row][l]) * gate[row][l] * W[h][l]
// grid (MTOT/64, 2): each wave does ONE head (h = blockIdx.y*4 + wave).
// ---------------------------------------------------------------------------
__global__ __launch_bounds__(256) void score_kernel(
    const short* __restrict__ mh, const short* __restrict__ gate_t,
    const short* __restrict__ Vt, const float* __restrict__ W,
    float* __restrict__ scores) {
  const int tid = threadIdx.x;
  const int lane = tid & 63;
  const int wv = tid >> 6;         // 0..3
  const int r = lane & 15, q = lane >> 4;
  const int row0 = blockIdx.x * 64;
  const int h = blockIdx.y * 4 + wv;

  float wc[8];
  #pragma unroll
  for (int ct = 0; ct < 8; ++ct) wc[ct] = W[(size_t)h * DL + 16 * ct + r];

  #pragma unroll
  for (int rt = 0; rt < 4; ++rt) {
    const short* ap = mh + ((size_t)h * MTOT + row0 + 16 * rt + r) * DM + q * 8;
    bf16x8 a0 = *reinterpret_cast<const bf16x8*>(ap);
    bf16x8 a1 = *reinterpret_cast<const bf16x8*>(ap + 32);
    float sc[4] = {0.f, 0.f, 0.f, 0.f};
    #pragma unroll
    for (int ct = 0; ct < 8; ++ct) {
      const short* bp = Vt + (size_t)(16 * ct + r) * DM + q * 8;
      bf16x8 b0 = *reinterpret_cast<const bf16x8*>(bp);
      bf16x8 b1 = *reinterpret_cast<const bf16x8*>(bp + 32);
      f32x4 t = f32x4{0.f, 0.f, 0.f, 0.f};
      t = mfma_bf16(a0, b0, t);
      t = mfma_bf16(a1, b1, t);
      s16x4 ga = *reinterpret_cast<const s16x4*>(
          gate_t + (size_t)(16 * ct + r) * MTOT + row0 + 16 * rt + 4 * q);
      #pragma unroll
      for (int j = 0; j < 4; ++j) {
        float g = b2f((j == 0) ? ga.x : (j == 1) ? ga.y : (j == 2) ? ga.z : ga.w);
        sc[j] += fast_tanh(t[j]) * g * wc[ct];
      }
    }
    #pragma unroll
    for (int j = 0; j < 4; ++j) {
      sc[j] += __shfl_xor(sc[j], 1);
      sc[j] += __shfl_xor(sc[j], 2);
      sc[j] += __shfl_xor(sc[j], 4);
      sc[j] += __shfl_xor(sc[j], 8);
    }
    if (r < 4) {
      float v = (r == 0) ? sc[0] : (r == 1) ? sc[1] : (r == 2) ? sc[2] : sc[3];
      scores[(size_t)h * MTOT + row0 + 16 * rt + 4 * q + r] = v;
    }
  }
}

// ---------------------------------------------------------------------------
// Kernel 4: masked softmax over N per (h,b). soft=0 for n >= true_num[b].
// ---------------------------------------------------------------------------
__global__ __launch_bounds__(256) void softmax_kernel(
    const float* __restrict__ scores, const int* __restrict__ true_num,
    float* __restrict__ soft, float* __restrict__ out_soft) {
  const int h = blockIdx.x >> 3, b = blockIdx.x & 7;
  const int tid = threadIdx.x;
  const int tn = true_num[b];
  const float* s = scores + ((size_t)h * BBAG + b) * NINST;
  __shared__ float red[8];

  float vals[16];
  float mx = -3.0e38f;
  #pragma unroll
  for (int i = 0; i < 16; ++i) {
    int n = tid + i * 256;
    float v = s[n];
    vals[i] = (n < tn) ? v : -3.0e38f;
    mx = fmaxf(mx, vals[i]);
  }
  #pragma unroll
  for (int m = 1; m < 64; m <<= 1) mx = fmaxf(mx, __shfl_xor(mx, m));
  if ((tid & 63) == 0) red[tid >> 6] = mx;
  __syncthreads();
  mx = fmaxf(fmaxf(red[0], red[1]), fmaxf(red[2], red[3]));

  float sum = 0.f;
  #pragma unroll
  for (int i = 0; i < 16; ++i) {
    int n = tid + i * 256;
    float e = (n < tn) ? expf(vals[i] - mx) : 0.0f;
    vals[i] = e;
    sum += e;
  }
  #pragma unroll
  for (int m = 1; m < 64; m <<= 1) sum += __shfl_xor(sum, m);
  if ((tid & 63) == 0) red[4 + (tid >> 6)] = sum;
  __syncthreads();
  sum = red[4] + red[5] + red[6] + red[7];
  float inv = 1.0f / sum;

  float* so = soft + ((size_t)h * BBAG + b) * NINST;
  #pragma unroll
  for (int i = 0; i < 16; ++i) {
    int n = tid + i * 256;
    float v = vals[i] * inv;
    so[n] = v;
    if (h == 0) out_soft[(size_t)b * NINST + n] = v;
  }
}

// ---------------------------------------------------------------------------
// Kernel 5a: partial pooling. grid = (h,b,chunk): 8*8*16 = 1024 blocks.
// ---------------------------------------------------------------------------
__global__ __launch_bounds__(256) void pool_partial(
    const short* __restrict__ mh, const float* __restrict__ soft,
    float* __restrict__ part) {
  const int c = blockIdx.x & (NCHUNK - 1);
  const int hb = blockIdx.x / NCHUNK;        // h*8 + b
  const int h = hb >> 3, b = hb & 7;
  const int tid = threadIdx.x;
  const int m = tid & 63, g = tid >> 6;
  const int n0 = c * (NINST / NCHUNK);
  const float* so = soft + ((size_t)h * BBAG + b) * NINST;
  const short* mp = mh + ((size_t)h * MTOT + (size_t)b * NINST) * DM;
  float acc = 0.f;
  #pragma unroll 4
  for (int n = n0 + g; n < n0 + NINST / NCHUNK; n += 4) {
    acc += so[n] * b2f(mp[(size_t)n * DM + m]);
  }
  __shared__ float red[256];
  red[tid] = acc;
  __syncthreads();
  if (tid < 64) {
    part[(size_t)(hb * NCHUNK + c) * DM + tid] =
        red[tid] + red[tid + 64] + red[tid + 128] + red[tid + 192];
  }
}

// ---------------------------------------------------------------------------
// Kernel 5b: reduce partials -> feat[b][h*64+m]
// ---------------------------------------------------------------------------
__global__ __launch_bounds__(256) void pool_reduce(
    const float* __restrict__ part, float* __restrict__ out_feat) {
  int g = blockIdx.x * blockDim.x + threadIdx.x;   // 4096 outputs
  int hb = g >> 6, m = g & 63;
  int h = hb >> 3, b = hb & 7;
  float s = 0.f;
  #pragma unroll
  for (int c = 0; c < NCHUNK; ++c)
    s += part[(size_t)(hb * NCHUNK + c) * DM + m];
  out_feat[(size_t)b * (NHEAD * DM) + h * DM + m] = s;
}

// ---------------------------------------------------------------------------
extern "C" void kernel_launch(void* const* d_in, const int* in_sizes, int n_in,
                              void* d_out, int out_size, void* d_ws, size_t ws_size,
                              hipStream_t stream) {
  (void)in_sizes; (void)n_in; (void)out_size; (void)ws_size;
  const float* x      = (const float*)d_in[0];
  const float* WX     = (const float*)d_in[1];
  const float* V      = (const float*)d_in[2];
  const float* W      = (const float*)d_in[3];
  const float* gate_w = (const float*)d_in[4];
  const int* true_num = (const int*)d_in[5];
  float* out = (float*)d_out;

  char* ws = (char*)d_ws;
  short* Wt2    = (short*)ws;  ws += (size_t)NCOL * DIM * 2;            //    655,360 B
  short* Vt     = (short*)ws;  ws += (size_t)DL * DM * 2;               //     16,384 B
  short* mh     = (short*)ws;  ws += (size_t)NHEAD * MTOT * DM * 2;     // 33,554,432 B
  short* gate_t = (short*)ws;  ws += (size_t)DL * MTOT * 2;             //  8,388,608 B
  float* scores = (float*)ws;  ws += (size_t)NHEAD * MTOT * 4;          //  1,048,576 B
  float* soft   = (float*)ws;  ws += (size_t)NHEAD * MTOT * 4;          //  1,048,576 B
  float* part   = (float*)ws;  ws += (size_t)NHEAD * BBAG * NCHUNK * DM * 4; // 524,288 B

  prep_weights<<<dim3(145), dim3(256), 0, stream>>>(WX, V, gate_w, Wt2, Vt);
  proj_kernel<<<dim3(MTOT / 64), dim3(512), 0, stream>>>(x, Wt2, mh, gate_t);
  score_kernel<<<dim3(MTOT / 64, 2), dim3(256), 0, stream>>>(mh, gate_t, Vt, W, scores);
  softmax_kernel<<<dim3(NHEAD * BBAG), dim3(256), 0, stream>>>(
      scores, true_num, soft, out + BBAG * NHEAD * DM);
  pool_partial<<<dim3(NHEAD * BBAG * NCHUNK), dim3(256), 0, stream>>>(mh, soft, part);
  pool_reduce<<<dim3(NHEAD * BBAG * DM / 256), dim3(256), 0, stream>>>(part, out);
}

// Round 16
// 85.702 us; speedup vs baseline: 1.7352x; 1.1577x over previous
//
#include <hip/hip_runtime.h>
#include <hip/hip_bf16.h>

#define DIM   512
#define NHEAD 8
#define DM    64
#define DL    128
#define BBAG  8
#define NINST 4096
#define MTOT  (BBAG*NINST)     // 32768 instances
#define NCOL  (NHEAD*DM + DL)  // 640 fused output columns (8*64 mh + 128 gate)
#define NCHUNK 16              // pool n-chunks per (h,b)

typedef short   bf16x8 __attribute__((ext_vector_type(8)));
typedef __bf16  bf16v8 __attribute__((ext_vector_type(8)));
typedef float   f32x4  __attribute__((ext_vector_type(4)));
typedef short   s16x4  __attribute__((ext_vector_type(4)));

__device__ __forceinline__ short f2b(float f) {
  __hip_bfloat16 h = __float2bfloat16(f);
  return __builtin_bit_cast(short, h);
}
__device__ __forceinline__ float b2f(short s) {
  __hip_bfloat16 h = __builtin_bit_cast(__hip_bfloat16, s);
  return __bfloat162float(h);
}
__device__ __forceinline__ f32x4 mfma_bf16(bf16x8 a, bf16x8 b, f32x4 c) {
  return __builtin_amdgcn_mfma_f32_16x16x32_bf16(
      __builtin_bit_cast(bf16v8, a), __builtin_bit_cast(bf16v8, b), c, 0, 0, 0);
}
__device__ __forceinline__ float fast_tanh(float x) {
  float t = __expf(2.0f * x);
  return 1.0f - 2.0f * __builtin_amdgcn_rcpf(t + 1.0f);
}
__device__ __forceinline__ float fast_sigmoid(float x) {
  return __builtin_amdgcn_rcpf(1.0f + __expf(-x));
}

// ---------------------------------------------------------------------------
// Kernel 1: build Wt2 (proj B, pre-swizzled slabs — R9 validated) and
// Vt_f (score B, FRAGMENT-PACKED: [ct*2+half][lane][8] -> 16B/lane coalesced).
// ---------------------------------------------------------------------------
__global__ __launch_bounds__(256) void prep_weights(
    const float* __restrict__ WX, const float* __restrict__ V,
    const float* __restrict__ gate_w,
    short* __restrict__ Wt2, short* __restrict__ Vt_f) {
  __shared__ float lds[32 * 129];
  const int bid = blockIdx.x, t = threadIdx.x;

  if (bid < 128) {
    const int h = bid >> 4, ks = bid & 15;
    {
      const int kl = t >> 3, m8 = (t & 7) * 8;
      const float* src = WX + ((size_t)(h * DIM + ks * 32 + kl) * DM + m8);
      #pragma unroll
      for (int j = 0; j < 8; ++j) lds[kl * 129 + m8 + j] = src[j];
    }
    __syncthreads();
    {
      const int m = t >> 2, q = t & 3;
      const int col = h * 64 + m;
      const int q2 = (q + ((col & 15) >> 1)) & 3;
      short* dst = Wt2 + ks * 20480 + col * 32 + q2 * 8;
      #pragma unroll
      for (int j = 0; j < 8; ++j) dst[j] = f2b(lds[(q * 8 + j) * 129 + m]);
    }
  } else if (bid < 144) {
    const int ks = bid - 128;
    #pragma unroll
    for (int rep = 0; rep < 2; ++rep) {
      const int idx = rep * 2048 + t * 8;
      const int kl = idx >> 7, l8 = idx & 127;
      const float* src = gate_w + ((size_t)(ks * 32 + kl) * DL + l8);
      #pragma unroll
      for (int j = 0; j < 8; ++j) lds[kl * 129 + l8 + j] = src[j];
    }
    __syncthreads();
    #pragma unroll
    for (int rep = 0; rep < 2; ++rep) {
      const int piece = rep * 256 + t;
      const int l = piece >> 2, q = piece & 3;
      const int col = 512 + l;
      const int q2 = (q + ((col & 15) >> 1)) & 3;
      short* dst = Wt2 + ks * 20480 + col * 32 + q2 * 8;
      #pragma unroll
      for (int j = 0; j < 8; ++j) dst[j] = f2b(lds[(q * 8 + j) * 129 + l]);
    }
  } else {
    // Vt_f: entry e = (ct*2+half)*64 + lane; holds V[m=half*32+q*8+j][l=16ct+r]
    #pragma unroll
    for (int rep = 0; rep < 4; ++rep) {
      const int e = t + rep * 256;
      const int ct = e >> 7, half = (e >> 6) & 1, lane = e & 63;
      const int r = lane & 15, q = lane >> 4;
      short* dst = Vt_f + (size_t)e * 8;
      #pragma unroll
      for (int j = 0; j < 8; ++j) {
        const int m = half * 32 + q * 8 + j;
        dst[j] = f2b(V[(size_t)m * DL + ct * 16 + r]);
      }
    }
  }
}

// ---------------------------------------------------------------------------
// Kernel 2: fused projection GEMM  C[32768 x 640] = x[32768 x 512] * Wcat
// BM=64, 512 thr = 8 waves (1x8 col split, B-dedup'd), acc[4][5].
// B pipeline PINNED with inline-asm global_load_dwordx4 (compiler cannot
// sink volatile asm) + depth-2 counted s_waitcnt vmcnt + sched_barrier.
// A staged once in 64 KB LDS (swizzled). gate written FRAGMENT-PACKED.
// ---------------------------------------------------------------------------
#define BLOAD(dst, addr) \
  asm volatile("global_load_dwordx4 %0, %1, off" : "=v"(dst) : "v"(addr))

__global__ __launch_bounds__(512) void proj_kernel(
    const float* __restrict__ x, const short* __restrict__ Wt2,
    short* __restrict__ mh, short* __restrict__ gate_f) {
  __shared__ alignas(16) short lds_a[32768];   // 64 KB: 16 slabs [64r][32k] swz
  const int tid = threadIdx.x;
  const int bm0 = blockIdx.x * 64;
  const int lane = tid & 63;
  const int w = tid >> 6;            // wave 0..7 -> cols [80w, 80w+80)
  const int r = lane & 15;
  const int q = lane >> 4;           // 0..3
  const int swzs = (q + (r >> 1)) & 3;
  char* lda = reinterpret_cast<char*>(lds_a);

  // ---- prologue: stage A tile (64 rows x 512 k) f32 -> bf16 LDS, swizzled.
  {
    const int arow = tid >> 3, ap = tid & 7;
    const int aslot = ((ap >> 1) + ((arow & 15) >> 1)) & 3;
    const float* asrc = x + ((size_t)(bm0 + arow) << 9) + (ap << 2);
    char* adst = lda + arow * 64 + aslot * 16 + (ap & 1) * 8;
    #pragma unroll
    for (int ks = 0; ks < 16; ++ks) {
      f32x4 v = *reinterpret_cast<const f32x4*>(asrc + ks * 32);
      s16x4 sv; sv.x = f2b(v[0]); sv.y = f2b(v[1]); sv.z = f2b(v[2]); sv.w = f2b(v[3]);
      *reinterpret_cast<s16x4*>(adst + ks * 4096) = sv;
    }
  }
  __syncthreads();   // drains prologue vmem; asm ledger starts at 0

  const short* bbase = Wt2 + (80 * w + r) * 32 + swzs * 8;
  bf16x8 bufs[3][5];

  // issue L(0), L(1): out = 10
  #pragma unroll
  for (int ct = 0; ct < 5; ++ct) BLOAD(bufs[0][ct], bbase + 0 * 20480 + ct * 512);
  #pragma unroll
  for (int ct = 0; ct < 5; ++ct) BLOAD(bufs[1][ct], bbase + 1 * 20480 + ct * 512);

  const int aoff = r * 64 + swzs * 16;
  bf16x8 afb[2][4];
  #pragma unroll
  for (int rt = 0; rt < 4; ++rt)
    afb[0][rt] = *reinterpret_cast<const bf16x8*>(lda + 0 * 4096 + aoff + rt * 1024);

  f32x4 acc[4][5];
  #pragma unroll
  for (int rt = 0; rt < 4; ++rt)
    #pragma unroll
    for (int ct = 0; ct < 5; ++ct) acc[rt][ct] = f32x4{0.f, 0.f, 0.f, 0.f};

  #pragma unroll
  for (int ks = 0; ks < 16; ++ks) {
    if (ks + 2 < 16) {
      #pragma unroll
      for (int ct = 0; ct < 5; ++ct)
        BLOAD(bufs[(ks + 2) % 3][ct], bbase + (ks + 2) * 20480 + ct * 512);
    }
    // counted wait: L(ks) retired (ledger: 15->10, tail 10->5, 5->0)
    if (ks < 14)      asm volatile("s_waitcnt vmcnt(10)" ::: "memory");
    else if (ks < 15) asm volatile("s_waitcnt vmcnt(5)" ::: "memory");
    else              asm volatile("s_waitcnt vmcnt(0)" ::: "memory");
    __builtin_amdgcn_sched_barrier(0);

    if (ks + 1 < 16) {
      #pragma unroll
      for (int rt = 0; rt < 4; ++rt)
        afb[(ks + 1) & 1][rt] = *reinterpret_cast<const bf16x8*>(
            lda + (ks + 1) * 4096 + aoff + rt * 1024);
    }
    #pragma unroll
    for (int ct = 0; ct < 5; ++ct)
      #pragma unroll
      for (int rt = 0; rt < 4; ++rt)
        acc[rt][ct] = mfma_bf16(afb[ks & 1][rt], bufs[ks % 3][ct], acc[rt][ct]);
  }

  // epilogue: D row = 16rt+4q+j, col = 80w+16ct+r
  #pragma unroll
  for (int rt = 0; rt < 4; ++rt) {
    #pragma unroll
    for (int ct = 0; ct < 5; ++ct) {
      const int colbase = 80 * w + 16 * ct;
      const int grow0 = bm0 + 16 * rt + 4 * q;
      if (colbase < NHEAD * DM) {
        const int col = colbase + r;
        #pragma unroll
        for (int j = 0; j < 4; ++j)
          mh[((size_t)(col >> 6) * MTOT + grow0 + j) * DM + (col & 63)] =
              f2b(acc[rt][ct][j]);
      } else {
        // fragment-packed gate: tile = (global row-tile, l-tile)
        const int rtile = (bm0 >> 4) + rt;          // blockIdx.x*4 + rt
        const int ltile = 5 * w + ct - 32;          // (colbase-512)/16
        s16x4 gv;
        gv.x = f2b(fast_sigmoid(acc[rt][ct][0]));
        gv.y = f2b(fast_sigmoid(acc[rt][ct][1]));
        gv.z = f2b(fast_sigmoid(acc[rt][ct][2]));
        gv.w = f2b(fast_sigmoid(acc[rt][ct][3]));
        *reinterpret_cast<s16x4*>(
            gate_f + ((size_t)(rtile * 8 + ltile) * 64 + lane) * 4) = gv;
      }
    }
  }
}

// ---------------------------------------------------------------------------
// Kernel 3: scores[h][row] = sum_l tanh((mh_h.V)[row][l]) * gate[row][l] * W[h][l]
// grid (MTOT/64, 2); wave = 1 head. ALL operand loads fragment-coalesced:
// mh rows (2KB/instr-pair), Vt_f (1KB/instr), gate_f (512B/instr).
// ---------------------------------------------------------------------------
__global__ __launch_bounds__(256) void score_kernel(
    const short* __restrict__ mh, const short* __restrict__ gate_f,
    const short* __restrict__ Vt_f, const float* __restrict__ W,
    float* __restrict__ scores) {
  const int tid = threadIdx.x;
  const int lane = tid & 63;
  const int wv = tid >> 6;         // 0..3
  const int r = lane & 15, q = lane >> 4;
  const int row0 = blockIdx.x * 64;
  const int h = blockIdx.y * 4 + wv;

  float wc[8];
  #pragma unroll
  for (int ct = 0; ct < 8; ++ct) wc[ct] = W[(size_t)h * DL + 16 * ct + r];

  // A-fragments for all 4 row-tiles (coalesced: 16 rows x 128B per pair)
  bf16x8 a0[4], a1[4];
  #pragma unroll
  for (int rt = 0; rt < 4; ++rt) {
    const short* ap = mh + ((size_t)h * MTOT + row0 + 16 * rt + r) * DM + q * 8;
    a0[rt] = *reinterpret_cast<const bf16x8*>(ap);
    a1[rt] = *reinterpret_cast<const bf16x8*>(ap + 32);
  }

  float sc[4][4];
  #pragma unroll
  for (int rt = 0; rt < 4; ++rt)
    #pragma unroll
    for (int j = 0; j < 4; ++j) sc[rt][j] = 0.f;

  #pragma unroll
  for (int ct = 0; ct < 8; ++ct) {
    bf16x8 b0 = *reinterpret_cast<const bf16x8*>(Vt_f + (size_t)(ct * 2) * 512 + lane * 8);
    bf16x8 b1 = *reinterpret_cast<const bf16x8*>(Vt_f + (size_t)(ct * 2 + 1) * 512 + lane * 8);
    #pragma unroll
    for (int rt = 0; rt < 4; ++rt) {
      f32x4 t = f32x4{0.f, 0.f, 0.f, 0.f};
      t = mfma_bf16(a0[rt], b0, t);
      t = mfma_bf16(a1[rt], b1, t);
      const int rtile = (row0 >> 4) + rt;
      s16x4 ga = *reinterpret_cast<const s16x4*>(
          gate_f + ((size_t)(rtile * 8 + ct) * 64 + lane) * 4);
      #pragma unroll
      for (int j = 0; j < 4; ++j) {
        float g = b2f((j == 0) ? ga.x : (j == 1) ? ga.y : (j == 2) ? ga.z : ga.w);
        sc[rt][j] += fast_tanh(t[j]) * g * wc[ct];
      }
    }
  }

  #pragma unroll
  for (int rt = 0; rt < 4; ++rt) {
    #pragma unroll
    for (int j = 0; j < 4; ++j) {
      sc[rt][j] += __shfl_xor(sc[rt][j], 1);
      sc[rt][j] += __shfl_xor(sc[rt][j], 2);
      sc[rt][j] += __shfl_xor(sc[rt][j], 4);
      sc[rt][j] += __shfl_xor(sc[rt][j], 8);
    }
    if (r < 4) {
      float v = (r == 0) ? sc[rt][0] : (r == 1) ? sc[rt][1]
              : (r == 2) ? sc[rt][2] : sc[rt][3];
      scores[(size_t)h * MTOT + row0 + 16 * rt + 4 * q + r] = v;
    }
  }
}

// ---------------------------------------------------------------------------
// Kernel 4: masked softmax over N per (h,b). soft=0 for n >= true_num[b].
// ---------------------------------------------------------------------------
__global__ __launch_bounds__(256) void softmax_kernel(
    const float* __restrict__ scores, const int* __restrict__ true_num,
    float* __restrict__ soft, float* __restrict__ out_soft) {
  const int h = blockIdx.x >> 3, b = blockIdx.x & 7;
  const int tid = threadIdx.x;
  const int tn = true_num[b];
  const float* s = scores + ((size_t)h * BBAG + b) * NINST;
  __shared__ float red[8];

  float vals[16];
  float mx = -3.0e38f;
  #pragma unroll
  for (int i = 0; i < 16; ++i) {
    int n = tid + i * 256;
    float v = s[n];
    vals[i] = (n < tn) ? v : -3.0e38f;
    mx = fmaxf(mx, vals[i]);
  }
  #pragma unroll
  for (int m = 1; m < 64; m <<= 1) mx = fmaxf(mx, __shfl_xor(mx, m));
  if ((tid & 63) == 0) red[tid >> 6] = mx;
  __syncthreads();
  mx = fmaxf(fmaxf(red[0], red[1]), fmaxf(red[2], red[3]));

  float sum = 0.f;
  #pragma unroll
  for (int i = 0; i < 16; ++i) {
    int n = tid + i * 256;
    float e = (n < tn) ? expf(vals[i] - mx) : 0.0f;
    vals[i] = e;
    sum += e;
  }
  #pragma unroll
  for (int m = 1; m < 64; m <<= 1) sum += __shfl_xor(sum, m);
  if ((tid & 63) == 0) red[4 + (tid >> 6)] = sum;
  __syncthreads();
  sum = red[4] + red[5] + red[6] + red[7];
  float inv = 1.0f / sum;

  float* so = soft + ((size_t)h * BBAG + b) * NINST;
  #pragma unroll
  for (int i = 0; i < 16; ++i) {
    int n = tid + i * 256;
    float v = vals[i] * inv;
    so[n] = v;
    if (h == 0) out_soft[(size_t)b * NINST + n] = v;
  }
}

// ---------------------------------------------------------------------------
// Kernel 5a: partial pooling. grid = (h,b,chunk): 8*8*16 = 1024 blocks.
// ---------------------------------------------------------------------------
__global__ __launch_bounds__(256) void pool_partial(
    const short* __restrict__ mh, const float* __restrict__ soft,
    float* __restrict__ part) {
  const int c = blockIdx.x & (NCHUNK - 1);
  const int hb = blockIdx.x / NCHUNK;        // h*8 + b
  const int h = hb >> 3, b = hb & 7;
  const int tid = threadIdx.x;
  const int m = tid & 63, g = tid >> 6;
  const int n0 = c * (NINST / NCHUNK);
  const float* so = soft + ((size_t)h * BBAG + b) * NINST;
  const short* mp = mh + ((size_t)h * MTOT + (size_t)b * NINST) * DM;
  float acc = 0.f;
  #pragma unroll 4
  for (int n = n0 + g; n < n0 + NINST / NCHUNK; n += 4) {
    acc += so[n] * b2f(mp[(size_t)n * DM + m]);
  }
  __shared__ float red[256];
  red[tid] = acc;
  __syncthreads();
  if (tid < 64) {
    part[(size_t)(hb * NCHUNK + c) * DM + tid] =
        red[tid] + red[tid + 64] + red[tid + 128] + red[tid + 192];
  }
}

// ---------------------------------------------------------------------------
// Kernel 5b: reduce partials -> feat[b][h*64+m]
// ---------------------------------------------------------------------------
__global__ __launch_bounds__(256) void pool_reduce(
    const float* __restrict__ part, float* __restrict__ out_feat) {
  int g = blockIdx.x * blockDim.x + threadIdx.x;   // 4096 outputs
  int hb = g >> 6, m = g & 63;
  int h = hb >> 3, b = hb & 7;
  float s = 0.f;
  #pragma unroll
  for (int c = 0; c < NCHUNK; ++c)
    s += part[(size_t)(hb * NCHUNK + c) * DM + m];
  out_feat[(size_t)b * (NHEAD * DM) + h * DM + m] = s;
}

// ---------------------------------------------------------------------------
extern "C" void kernel_launch(void* const* d_in, const int* in_sizes, int n_in,
                              void* d_out, int out_size, void* d_ws, size_t ws_size,
                              hipStream_t stream) {
  (void)in_sizes; (void)n_in; (void)out_size; (void)ws_size;
  const float* x      = (const float*)d_in[0];
  const float* WX     = (const float*)d_in[1];
  const float* V      = (const float*)d_in[2];
  const float* W      = (const float*)d_in[3];
  const float* gate_w = (const float*)d_in[4];
  const int* true_num = (const int*)d_in[5];
  float* out = (float*)d_out;

  char* ws = (char*)d_ws;
  short* Wt2    = (short*)ws;  ws += (size_t)NCOL * DIM * 2;            //    655,360 B
  short* Vt_f   = (short*)ws;  ws += (size_t)DL * DM * 2;               //     16,384 B
  short* mh     = (short*)ws;  ws += (size_t)NHEAD * MTOT * DM * 2;     // 33,554,432 B
  short* gate_f = (short*)ws;  ws += (size_t)DL * MTOT * 2;             //  8,388,608 B
  float* scores = (float*)ws;  ws += (size_t)NHEAD * MTOT * 4;          //  1,048,576 B
  float* soft   = (float*)ws;  ws += (size_t)NHEAD * MTOT * 4;          //  1,048,576 B
  float* part   = (float*)ws;  ws += (size_t)NHEAD * BBAG * NCHUNK * DM * 4; // 524,288 B

  prep_weights<<<dim3(145), dim3(256), 0, stream>>>(WX, V, gate_w, Wt2, Vt_f);
  proj_kernel<<<dim3(MTOT / 64), dim3(512), 0, stream>>>(x, Wt2, mh, gate_f);
  score_kernel<<<dim3(MTOT / 64, 2), dim3(256), 0, stream>>>(mh, gate_f, Vt_f, W, scores);
  softmax_kernel<<<dim3(NHEAD * BBAG), dim3(256), 0, stream>>>(
      scores, true_num, soft, out + BBAG * NHEAD * DM);
  pool_partial<<<dim3(NHEAD * BBAG * NCHUNK), dim3(256), 0, stream>>>(mh, soft, part);
  pool_reduce<<<dim3(NHEAD * BBAG * DM / 256), dim3(256), 0, stream>>>(part, out);
}

// Round 17
// 71.819 us; speedup vs baseline: 2.0706x; 1.1933x over previous
//
#include <hip/hip_runtime.h>
#include <hip/hip_bf16.h>

#define DIM   512
#define NHEAD 8
#define DM    64
#define DL    128
#define BBAG  8
#define NINST 4096
#define MTOT  (BBAG*NINST)     // 32768 instances
#define NCOL  (NHEAD*DM + DL)  // 640 fused output columns (8*64 mh + 128 gate)
#define NCHUNK 16              // pool n-chunks per (h,b)
#define MH_PITCH 520           // shorts per mh_lds row (512 + 8 pad)

typedef short   bf16x8 __attribute__((ext_vector_type(8)));
typedef __bf16  bf16v8 __attribute__((ext_vector_type(8)));
typedef float   f32x4  __attribute__((ext_vector_type(4)));
typedef short   s16x4  __attribute__((ext_vector_type(4)));

__device__ __forceinline__ short f2b(float f) {
  __hip_bfloat16 h = __float2bfloat16(f);
  return __builtin_bit_cast(short, h);
}
__device__ __forceinline__ float b2f(short s) {
  __hip_bfloat16 h = __builtin_bit_cast(__hip_bfloat16, s);
  return __bfloat162float(h);
}
__device__ __forceinline__ f32x4 mfma_bf16(bf16x8 a, bf16x8 b, f32x4 c) {
  return __builtin_amdgcn_mfma_f32_16x16x32_bf16(
      __builtin_bit_cast(bf16v8, a), __builtin_bit_cast(bf16v8, b), c, 0, 0, 0);
}
__device__ __forceinline__ float fast_tanh(float x) {
  float t = __expf(2.0f * x);
  return 1.0f - 2.0f * __builtin_amdgcn_rcpf(t + 1.0f);
}
__device__ __forceinline__ float fast_sigmoid(float x) {
  return __builtin_amdgcn_rcpf(1.0f + __expf(-x));
}

// ---------------------------------------------------------------------------
// Kernel 1: build Wt2 (proj B, pre-swizzled slabs) and Vt_f (fragment-packed
// score B). Both validated on HW (R16, absmax 7.6e-6).
// ---------------------------------------------------------------------------
__global__ __launch_bounds__(256) void prep_weights(
    const float* __restrict__ WX, const float* __restrict__ V,
    const float* __restrict__ gate_w,
    short* __restrict__ Wt2, short* __restrict__ Vt_f) {
  __shared__ float lds[32 * 129];
  const int bid = blockIdx.x, t = threadIdx.x;

  if (bid < 128) {
    const int h = bid >> 4, ks = bid & 15;
    {
      const int kl = t >> 3, m8 = (t & 7) * 8;
      const float* src = WX + ((size_t)(h * DIM + ks * 32 + kl) * DM + m8);
      #pragma unroll
      for (int j = 0; j < 8; ++j) lds[kl * 129 + m8 + j] = src[j];
    }
    __syncthreads();
    {
      const int m = t >> 2, q = t & 3;
      const int col = h * 64 + m;
      const int q2 = (q + ((col & 15) >> 1)) & 3;
      short* dst = Wt2 + ks * 20480 + col * 32 + q2 * 8;
      #pragma unroll
      for (int j = 0; j < 8; ++j) dst[j] = f2b(lds[(q * 8 + j) * 129 + m]);
    }
  } else if (bid < 144) {
    const int ks = bid - 128;
    #pragma unroll
    for (int rep = 0; rep < 2; ++rep) {
      const int idx = rep * 2048 + t * 8;
      const int kl = idx >> 7, l8 = idx & 127;
      const float* src = gate_w + ((size_t)(ks * 32 + kl) * DL + l8);
      #pragma unroll
      for (int j = 0; j < 8; ++j) lds[kl * 129 + l8 + j] = src[j];
    }
    __syncthreads();
    #pragma unroll
    for (int rep = 0; rep < 2; ++rep) {
      const int piece = rep * 256 + t;
      const int l = piece >> 2, q = piece & 3;
      const int col = 512 + l;
      const int q2 = (q + ((col & 15) >> 1)) & 3;
      short* dst = Wt2 + ks * 20480 + col * 32 + q2 * 8;
      #pragma unroll
      for (int j = 0; j < 8; ++j) dst[j] = f2b(lds[(q * 8 + j) * 129 + l]);
    }
  } else {
    // Vt_f: entry e = (ct*2+half)*64 + lane; holds V[m=half*32+q*8+j][l=16ct+r]
    #pragma unroll
    for (int rep = 0; rep < 4; ++rep) {
      const int e = t + rep * 256;
      const int ct = e >> 7, half = (e >> 6) & 1, lane = e & 63;
      const int r = lane & 15, q = lane >> 4;
      short* dst = Vt_f + (size_t)e * 8;
      #pragma unroll
      for (int j = 0; j < 8; ++j) {
        const int m = half * 32 + q * 8 + j;
        dst[j] = f2b(V[(size_t)m * DL + ct * 16 + r]);
      }
    }
  }
}

// ---------------------------------------------------------------------------
// Kernel 2 (FUSED proj + score): per 64-row block, the K-loop computes ALL
// 640 output cols (mh + gate) in-block; epilogue redistributes mh (row-major
// [64][520] LDS, pad => <=2-way) and gate (fragment-packed LDS tiles) and the
// score phase (wave w = head w) computes tanh(mh.V)*gate . W in-block.
// Eliminates the 50 MB mh/gate global round-trip of the split design.
// LDS: phase 1 = A-stage [0,32768) shorts; phase 2 = mh [0,33280) + gate
// [33280,41472). Barriers separate the phases.
// ---------------------------------------------------------------------------
#define BLOAD(dst, addr) \
  asm volatile("global_load_dwordx4 %0, %1, off" : "=v"(dst) : "v"(addr))

__global__ __launch_bounds__(512) void proj_score_kernel(
    const float* __restrict__ x, const short* __restrict__ Wt2,
    const short* __restrict__ Vt_f, const float* __restrict__ W,
    short* __restrict__ mh, float* __restrict__ scores) {
  __shared__ alignas(16) short lds[41472];   // 82,944 B
  const int tid = threadIdx.x;
  const int bm0 = blockIdx.x * 64;
  const int lane = tid & 63;
  const int w = tid >> 6;            // wave 0..7 -> cols [80w, 80w+80); head w
  const int r = lane & 15;
  const int q = lane >> 4;           // 0..3
  const int swzs = (q + (r >> 1)) & 3;
  char* lda = reinterpret_cast<char*>(lds);
  short* mh_lds = lds;               // [64][MH_PITCH]
  short* gate_lds = lds + 64 * MH_PITCH;  // 32 tiles * 64 lanes * 4

  // ---- phase 1 prologue: stage A tile (64x512) f32 -> bf16 LDS, swizzled.
  {
    const int arow = tid >> 3, ap = tid & 7;
    const int aslot = ((ap >> 1) + ((arow & 15) >> 1)) & 3;
    const float* asrc = x + ((size_t)(bm0 + arow) << 9) + (ap << 2);
    char* adst = lda + arow * 64 + aslot * 16 + (ap & 1) * 8;
    #pragma unroll
    for (int ks = 0; ks < 16; ++ks) {
      f32x4 v = *reinterpret_cast<const f32x4*>(asrc + ks * 32);
      s16x4 sv; sv.x = f2b(v[0]); sv.y = f2b(v[1]); sv.z = f2b(v[2]); sv.w = f2b(v[3]);
      *reinterpret_cast<s16x4*>(adst + ks * 4096) = sv;
    }
  }
  __syncthreads();   // drains prologue vmem; asm ledger starts at 0

  const short* bbase = Wt2 + (80 * w + r) * 32 + swzs * 8;
  bf16x8 bufs[3][5];
  #pragma unroll
  for (int ct = 0; ct < 5; ++ct) BLOAD(bufs[0][ct], bbase + 0 * 20480 + ct * 512);
  #pragma unroll
  for (int ct = 0; ct < 5; ++ct) BLOAD(bufs[1][ct], bbase + 1 * 20480 + ct * 512);

  const int aoff = r * 64 + swzs * 16;
  bf16x8 afb[2][4];
  #pragma unroll
  for (int rt = 0; rt < 4; ++rt)
    afb[0][rt] = *reinterpret_cast<const bf16x8*>(lda + 0 * 4096 + aoff + rt * 1024);

  f32x4 acc[4][5];
  #pragma unroll
  for (int rt = 0; rt < 4; ++rt)
    #pragma unroll
    for (int ct = 0; ct < 5; ++ct) acc[rt][ct] = f32x4{0.f, 0.f, 0.f, 0.f};

  #pragma unroll
  for (int ks = 0; ks < 16; ++ks) {
    if (ks + 2 < 16) {
      #pragma unroll
      for (int ct = 0; ct < 5; ++ct)
        BLOAD(bufs[(ks + 2) % 3][ct], bbase + (ks + 2) * 20480 + ct * 512);
    }
    if (ks < 14)      asm volatile("s_waitcnt vmcnt(10)" ::: "memory");
    else if (ks < 15) asm volatile("s_waitcnt vmcnt(5)" ::: "memory");
    else              asm volatile("s_waitcnt vmcnt(0)" ::: "memory");
    __builtin_amdgcn_sched_barrier(0);

    if (ks + 1 < 16) {
      #pragma unroll
      for (int rt = 0; rt < 4; ++rt)
        afb[(ks + 1) & 1][rt] = *reinterpret_cast<const bf16x8*>(
            lda + (ks + 1) * 4096 + aoff + rt * 1024);
    }
    #pragma unroll
    for (int ct = 0; ct < 5; ++ct)
      #pragma unroll
      for (int rt = 0; rt < 4; ++rt)
        acc[rt][ct] = mfma_bf16(afb[ks & 1][rt], bufs[ks % 3][ct], acc[rt][ct]);
  }

  __syncthreads();   // all A-LDS reads done; safe to overwrite with mh_lds

  // ---- epilogue: mh -> global + LDS; gate -> LDS (fragment-packed) ----
  #pragma unroll
  for (int rt = 0; rt < 4; ++rt) {
    #pragma unroll
    for (int ct = 0; ct < 5; ++ct) {
      const int colbase = 80 * w + 16 * ct;
      const int grow0 = bm0 + 16 * rt + 4 * q;
      if (colbase < NHEAD * DM) {
        const int col = colbase + r;
        #pragma unroll
        for (int j = 0; j < 4; ++j) {
          const short bv = f2b(acc[rt][ct][j]);
          mh[((size_t)(col >> 6) * MTOT + grow0 + j) * DM + (col & 63)] = bv;
          mh_lds[(16 * rt + 4 * q + j) * MH_PITCH + col] = bv;
        }
      } else {
        const int ltile = 5 * w + ct - 32;          // (colbase-512)/16
        s16x4 gv;
        gv.x = f2b(fast_sigmoid(acc[rt][ct][0]));
        gv.y = f2b(fast_sigmoid(acc[rt][ct][1]));
        gv.z = f2b(fast_sigmoid(acc[rt][ct][2]));
        gv.w = f2b(fast_sigmoid(acc[rt][ct][3]));
        *reinterpret_cast<s16x4*>(
            gate_lds + ((rt * 8 + ltile) * 64 + lane) * 4) = gv;
      }
    }
  }
  __syncthreads();   // mh_lds + gate_lds complete

  // ---- score phase: wave w = head h = w, rows of this block ----
  const int h = w;
  float wc[8];
  #pragma unroll
  for (int lt = 0; lt < 8; ++lt) wc[lt] = W[(size_t)h * DL + 16 * lt + r];

  bf16x8 a0[4], a1[4];
  #pragma unroll
  for (int rt = 0; rt < 4; ++rt) {
    const short* ap = mh_lds + (16 * rt + r) * MH_PITCH + h * 64 + q * 8;
    a0[rt] = *reinterpret_cast<const bf16x8*>(ap);
    a1[rt] = *reinterpret_cast<const bf16x8*>(ap + 32);
  }

  float sc[4][4];
  #pragma unroll
  for (int rt = 0; rt < 4; ++rt)
    #pragma unroll
    for (int j = 0; j < 4; ++j) sc[rt][j] = 0.f;

  #pragma unroll
  for (int lt = 0; lt < 8; ++lt) {
    bf16x8 b0 = *reinterpret_cast<const bf16x8*>(Vt_f + (size_t)(lt * 2) * 512 + lane * 8);
    bf16x8 b1 = *reinterpret_cast<const bf16x8*>(Vt_f + (size_t)(lt * 2 + 1) * 512 + lane * 8);
    #pragma unroll
    for (int rt = 0; rt < 4; ++rt) {
      f32x4 t = f32x4{0.f, 0.f, 0.f, 0.f};
      t = mfma_bf16(a0[rt], b0, t);
      t = mfma_bf16(a1[rt], b1, t);
      s16x4 ga = *reinterpret_cast<const s16x4*>(
          gate_lds + ((rt * 8 + lt) * 64 + lane) * 4);
      #pragma unroll
      for (int j = 0; j < 4; ++j) {
        float g = b2f((j == 0) ? ga.x : (j == 1) ? ga.y : (j == 2) ? ga.z : ga.w);
        sc[rt][j] += fast_tanh(t[j]) * g * wc[lt];
      }
    }
  }

  #pragma unroll
  for (int rt = 0; rt < 4; ++rt) {
    #pragma unroll
    for (int j = 0; j < 4; ++j) {
      sc[rt][j] += __shfl_xor(sc[rt][j], 1);
      sc[rt][j] += __shfl_xor(sc[rt][j], 2);
      sc[rt][j] += __shfl_xor(sc[rt][j], 4);
      sc[rt][j] += __shfl_xor(sc[rt][j], 8);
    }
    if (r < 4) {
      float v = (r == 0) ? sc[rt][0] : (r == 1) ? sc[rt][1]
              : (r == 2) ? sc[rt][2] : sc[rt][3];
      scores[(size_t)h * MTOT + bm0 + 16 * rt + 4 * q + r] = v;
    }
  }
}

// ---------------------------------------------------------------------------
// Kernel 3: masked softmax over N per (h,b). soft=0 for n >= true_num[b].
// ---------------------------------------------------------------------------
__global__ __launch_bounds__(256) void softmax_kernel(
    const float* __restrict__ scores, const int* __restrict__ true_num,
    float* __restrict__ soft, float* __restrict__ out_soft) {
  const int h = blockIdx.x >> 3, b = blockIdx.x & 7;
  const int tid = threadIdx.x;
  const int tn = true_num[b];
  const float* s = scores + ((size_t)h * BBAG + b) * NINST;
  __shared__ float red[8];

  float vals[16];
  float mx = -3.0e38f;
  #pragma unroll
  for (int i = 0; i < 16; ++i) {
    int n = tid + i * 256;
    float v = s[n];
    vals[i] = (n < tn) ? v : -3.0e38f;
    mx = fmaxf(mx, vals[i]);
  }
  #pragma unroll
  for (int m = 1; m < 64; m <<= 1) mx = fmaxf(mx, __shfl_xor(mx, m));
  if ((tid & 63) == 0) red[tid >> 6] = mx;
  __syncthreads();
  mx = fmaxf(fmaxf(red[0], red[1]), fmaxf(red[2], red[3]));

  float sum = 0.f;
  #pragma unroll
  for (int i = 0; i < 16; ++i) {
    int n = tid + i * 256;
    float e = (n < tn) ? expf(vals[i] - mx) : 0.0f;
    vals[i] = e;
    sum += e;
  }
  #pragma unroll
  for (int m = 1; m < 64; m <<= 1) sum += __shfl_xor(sum, m);
  if ((tid & 63) == 0) red[4 + (tid >> 6)] = sum;
  __syncthreads();
  sum = red[4] + red[5] + red[6] + red[7];
  float inv = 1.0f / sum;

  float* so = soft + ((size_t)h * BBAG + b) * NINST;
  #pragma unroll
  for (int i = 0; i < 16; ++i) {
    int n = tid + i * 256;
    float v = vals[i] * inv;
    so[n] = v;
    if (h == 0) out_soft[(size_t)b * NINST + n] = v;
  }
}

// ---------------------------------------------------------------------------
// Kernel 4a: partial pooling. grid = (h,b,chunk): 8*8*16 = 1024 blocks.
// ---------------------------------------------------------------------------
__global__ __launch_bounds__(256) void pool_partial(
    const short* __restrict__ mh, const float* __restrict__ soft,
    float* __restrict__ part) {
  const int c = blockIdx.x & (NCHUNK - 1);
  const int hb = blockIdx.x / NCHUNK;        // h*8 + b
  const int h = hb >> 3, b = hb & 7;
  const int tid = threadIdx.x;
  const int m = tid & 63, g = tid >> 6;
  const int n0 = c * (NINST / NCHUNK);
  const float* so = soft + ((size_t)h * BBAG + b) * NINST;
  const short* mp = mh + ((size_t)h * MTOT + (size_t)b * NINST) * DM;
  float acc = 0.f;
  #pragma unroll 4
  for (int n = n0 + g; n < n0 + NINST / NCHUNK; n += 4) {
    acc += so[n] * b2f(mp[(size_t)n * DM + m]);
  }
  __shared__ float red[256];
  red[tid] = acc;
  __syncthreads();
  if (tid < 64) {
    part[(size_t)(hb * NCHUNK + c) * DM + tid] =
        red[tid] + red[tid + 64] + red[tid + 128] + red[tid + 192];
  }
}

// ---------------------------------------------------------------------------
// Kernel 4b: reduce partials -> feat[b][h*64+m]
// ---------------------------------------------------------------------------
__global__ __launch_bounds__(256) void pool_reduce(
    const float* __restrict__ part, float* __restrict__ out_feat) {
  int g = blockIdx.x * blockDim.x + threadIdx.x;   // 4096 outputs
  int hb = g >> 6, m = g & 63;
  int h = hb >> 3, b = hb & 7;
  float s = 0.f;
  #pragma unroll
  for (int c = 0; c < NCHUNK; ++c)
    s += part[(size_t)(hb * NCHUNK + c) * DM + m];
  out_feat[(size_t)b * (NHEAD * DM) + h * DM + m] = s;
}

// ---------------------------------------------------------------------------
extern "C" void kernel_launch(void* const* d_in, const int* in_sizes, int n_in,
                              void* d_out, int out_size, void* d_ws, size_t ws_size,
                              hipStream_t stream) {
  (void)in_sizes; (void)n_in; (void)out_size; (void)ws_size;
  const float* x      = (const float*)d_in[0];
  const float* WX     = (const float*)d_in[1];
  const float* V      = (const float*)d_in[2];
  const float* W      = (const float*)d_in[3];
  const float* gate_w = (const float*)d_in[4];
  const int* true_num = (const int*)d_in[5];
  float* out = (float*)d_out;

  char* ws = (char*)d_ws;
  short* Wt2    = (short*)ws;  ws += (size_t)NCOL * DIM * 2;            //    655,360 B
  short* Vt_f   = (short*)ws;  ws += (size_t)DL * DM * 2;               //     16,384 B
  short* mh     = (short*)ws;  ws += (size_t)NHEAD * MTOT * DM * 2;     // 33,554,432 B
  float* scores = (float*)ws;  ws += (size_t)NHEAD * MTOT * 4;          //  1,048,576 B
  float* soft   = (float*)ws;  ws += (size_t)NHEAD * MTOT * 4;          //  1,048,576 B
  float* part   = (float*)ws;  ws += (size_t)NHEAD * BBAG * NCHUNK * DM * 4; // 524,288 B

  prep_weights<<<dim3(145), dim3(256), 0, stream>>>(WX, V, gate_w, Wt2, Vt_f);
  proj_score_kernel<<<dim3(MTOT / 64), dim3(512), 0, stream>>>(
      x, Wt2, Vt_f, W, mh, scores);
  softmax_kernel<<<dim3(NHEAD * BBAG), dim3(256), 0, stream>>>(
      scores, true_num, soft, out + BBAG * NHEAD * DM);
  pool_partial<<<dim3(NHEAD * BBAG * NCHUNK), dim3(256), 0, stream>>>(mh, soft, part);
  pool_reduce<<<dim3(NHEAD * BBAG * DM / 256), dim3(256), 0, stream>>>(part, out);
}

// Round 18
// 66.078 us; speedup vs baseline: 2.2505x; 1.0869x over previous
//
#include <hip/hip_runtime.h>
#include <hip/hip_bf16.h>

#define DIM   512
#define NHEAD 8
#define DM    64
#define DL    128
#define BBAG  8
#define NINST 4096
#define MTOT  (BBAG*NINST)     // 32768 instances
#define NBLK  (MTOT/64)        // 512 fused blocks
#define MH_PITCH 520           // shorts per mh_lds row (512 + 8 pad)

typedef short   bf16x8 __attribute__((ext_vector_type(8)));
typedef __bf16  bf16v8 __attribute__((ext_vector_type(8)));
typedef float   f32x4  __attribute__((ext_vector_type(4)));
typedef short   s16x4  __attribute__((ext_vector_type(4)));

__device__ __forceinline__ short f2b(float f) {
  __hip_bfloat16 h = __float2bfloat16(f);
  return __builtin_bit_cast(short, h);
}
__device__ __forceinline__ float b2f(short s) {
  __hip_bfloat16 h = __builtin_bit_cast(__hip_bfloat16, s);
  return __bfloat162float(h);
}
__device__ __forceinline__ f32x4 mfma_bf16(bf16x8 a, bf16x8 b, f32x4 c) {
  return __builtin_amdgcn_mfma_f32_16x16x32_bf16(
      __builtin_bit_cast(bf16v8, a), __builtin_bit_cast(bf16v8, b), c, 0, 0, 0);
}
__device__ __forceinline__ float fast_tanh(float x) {
  float t = __expf(2.0f * x);
  return 1.0f - 2.0f * __builtin_amdgcn_rcpf(t + 1.0f);
}
__device__ __forceinline__ float fast_sigmoid(float x) {
  return __builtin_amdgcn_rcpf(1.0f + __expf(-x));
}

// ---------------------------------------------------------------------------
// Kernel 1: build Wt2 (proj B, pre-swizzled slabs) and Vt_f (fragment-packed
// score B). Both validated on HW (R16/R17, absmax 7.6e-6).
// ---------------------------------------------------------------------------
__global__ __launch_bounds__(256) void prep_weights(
    const float* __restrict__ WX, const float* __restrict__ V,
    const float* __restrict__ gate_w,
    short* __restrict__ Wt2, short* __restrict__ Vt_f) {
  __shared__ float lds[32 * 129];
  const int bid = blockIdx.x, t = threadIdx.x;

  if (bid < 128) {
    const int h = bid >> 4, ks = bid & 15;
    {
      const int kl = t >> 3, m8 = (t & 7) * 8;
      const float* src = WX + ((size_t)(h * DIM + ks * 32 + kl) * DM + m8);
      #pragma unroll
      for (int j = 0; j < 8; ++j) lds[kl * 129 + m8 + j] = src[j];
    }
    __syncthreads();
    {
      const int m = t >> 2, q = t & 3;
      const int col = h * 64 + m;
      const int q2 = (q + ((col & 15) >> 1)) & 3;
      short* dst = Wt2 + ks * 20480 + col * 32 + q2 * 8;
      #pragma unroll
      for (int j = 0; j < 8; ++j) dst[j] = f2b(lds[(q * 8 + j) * 129 + m]);
    }
  } else if (bid < 144) {
    const int ks = bid - 128;
    #pragma unroll
    for (int rep = 0; rep < 2; ++rep) {
      const int idx = rep * 2048 + t * 8;
      const int kl = idx >> 7, l8 = idx & 127;
      const float* src = gate_w + ((size_t)(ks * 32 + kl) * DL + l8);
      #pragma unroll
      for (int j = 0; j < 8; ++j) lds[kl * 129 + l8 + j] = src[j];
    }
    __syncthreads();
    #pragma unroll
    for (int rep = 0; rep < 2; ++rep) {
      const int piece = rep * 256 + t;
      const int l = piece >> 2, q = piece & 3;
      const int col = 512 + l;
      const int q2 = (q + ((col & 15) >> 1)) & 3;
      short* dst = Wt2 + ks * 20480 + col * 32 + q2 * 8;
      #pragma unroll
      for (int j = 0; j < 8; ++j) dst[j] = f2b(lds[(q * 8 + j) * 129 + l]);
    }
  } else {
    // Vt_f: entry e = (ct*2+half)*64 + lane; holds V[m=half*32+q*8+j][l=16ct+r]
    #pragma unroll
    for (int rep = 0; rep < 4; ++rep) {
      const int e = t + rep * 256;
      const int ct = e >> 7, half = (e >> 6) & 1, lane = e & 63;
      const int r = lane & 15, q = lane >> 4;
      short* dst = Vt_f + (size_t)e * 8;
      #pragma unroll
      for (int j = 0; j < 8; ++j) {
        const int m = half * 32 + q * 8 + j;
        dst[j] = f2b(V[(size_t)m * DL + ct * 16 + r]);
      }
    }
  }
}

// ---------------------------------------------------------------------------
// Kernel 2 (FULLY FUSED proj + score + softmax-numerator + partial-pool):
// per 64-row block (one bag b, all heads):
//   K-loop GEMM (R16-validated asm-pinned B pipeline) -> acc
//   epilogue -> mh_lds [64][520] + gate_lds (fragment-packed) — LDS ONLY
//   score phase (wave w = head w) -> s -> e = (n<true_num[b]) ? exp(s) : 0
//     (no max-subtraction: |s| analytically bounded; ratio identical)
//   pool phase: part[h][blk][m] = sum_rows e*mh ; esum[h][blk] = sum e
//   e0 (head-0 numerators) stored for the soft output.
// mh NEVER touches global memory (kills the 67 MB round-trip).
// ---------------------------------------------------------------------------
#define BLOAD(dst, addr) \
  asm volatile("global_load_dwordx4 %0, %1, off" : "=v"(dst) : "v"(addr))

__global__ __launch_bounds__(512) void fused_kernel(
    const float* __restrict__ x, const short* __restrict__ Wt2,
    const short* __restrict__ Vt_f, const float* __restrict__ W,
    const int* __restrict__ true_num,
    float* __restrict__ part, float* __restrict__ esum,
    float* __restrict__ e0) {
  __shared__ alignas(16) short lds[42496];   // 84,992 B
  const int tid = threadIdx.x;
  const int blk = blockIdx.x;
  const int bm0 = blk * 64;
  const int lane = tid & 63;
  const int w = tid >> 6;            // wave 0..7 -> cols [80w,80w+80); head w
  const int r = lane & 15;
  const int q = lane >> 4;           // 0..3
  const int swzs = (q + (r >> 1)) & 3;
  char* lda = reinterpret_cast<char*>(lds);
  short* mh_lds = lds;                        // [64][MH_PITCH]
  short* gate_lds = lds + 64 * MH_PITCH;      // 32 tiles * 64 lanes * 4
  float* e_lds = reinterpret_cast<float*>(lds + 64 * MH_PITCH + 8192); // [8][64]

  const int tn = true_num[blk >> 6];          // bag = blk/64
  const int nbase = bm0 & (NINST - 1);        // row offset within bag

  // ---- phase 1: stage A tile (64x512) f32 -> bf16 LDS, swizzled ----
  {
    const int arow = tid >> 3, ap = tid & 7;
    const int aslot = ((ap >> 1) + ((arow & 15) >> 1)) & 3;
    const float* asrc = x + ((size_t)(bm0 + arow) << 9) + (ap << 2);
    char* adst = lda + arow * 64 + aslot * 16 + (ap & 1) * 8;
    #pragma unroll
    for (int ks = 0; ks < 16; ++ks) {
      f32x4 v = *reinterpret_cast<const f32x4*>(asrc + ks * 32);
      s16x4 sv; sv.x = f2b(v[0]); sv.y = f2b(v[1]); sv.z = f2b(v[2]); sv.w = f2b(v[3]);
      *reinterpret_cast<s16x4*>(adst + ks * 4096) = sv;
    }
  }
  __syncthreads();   // drains prologue vmem; asm ledger starts at 0

  const short* bbase = Wt2 + (80 * w + r) * 32 + swzs * 8;
  bf16x8 bufs[3][5];
  #pragma unroll
  for (int ct = 0; ct < 5; ++ct) BLOAD(bufs[0][ct], bbase + 0 * 20480 + ct * 512);
  #pragma unroll
  for (int ct = 0; ct < 5; ++ct) BLOAD(bufs[1][ct], bbase + 1 * 20480 + ct * 512);

  const int aoff = r * 64 + swzs * 16;
  bf16x8 afb[2][4];
  #pragma unroll
  for (int rt = 0; rt < 4; ++rt)
    afb[0][rt] = *reinterpret_cast<const bf16x8*>(lda + 0 * 4096 + aoff + rt * 1024);

  f32x4 acc[4][5];
  #pragma unroll
  for (int rt = 0; rt < 4; ++rt)
    #pragma unroll
    for (int ct = 0; ct < 5; ++ct) acc[rt][ct] = f32x4{0.f, 0.f, 0.f, 0.f};

  #pragma unroll
  for (int ks = 0; ks < 16; ++ks) {
    if (ks + 2 < 16) {
      #pragma unroll
      for (int ct = 0; ct < 5; ++ct)
        BLOAD(bufs[(ks + 2) % 3][ct], bbase + (ks + 2) * 20480 + ct * 512);
    }
    if (ks < 14)      asm volatile("s_waitcnt vmcnt(10)" ::: "memory");
    else if (ks < 15) asm volatile("s_waitcnt vmcnt(5)" ::: "memory");
    else              asm volatile("s_waitcnt vmcnt(0)" ::: "memory");
    __builtin_amdgcn_sched_barrier(0);

    if (ks + 1 < 16) {
      #pragma unroll
      for (int rt = 0; rt < 4; ++rt)
        afb[(ks + 1) & 1][rt] = *reinterpret_cast<const bf16x8*>(
            lda + (ks + 1) * 4096 + aoff + rt * 1024);
    }
    #pragma unroll
    for (int ct = 0; ct < 5; ++ct)
      #pragma unroll
      for (int rt = 0; rt < 4; ++rt)
        acc[rt][ct] = mfma_bf16(afb[ks & 1][rt], bufs[ks % 3][ct], acc[rt][ct]);
  }

  __syncthreads();   // A-LDS reads done; safe to overwrite with mh_lds

  // ---- epilogue: mh -> LDS (row-major); gate -> LDS (fragment-packed) ----
  #pragma unroll
  for (int rt = 0; rt < 4; ++rt) {
    #pragma unroll
    for (int ct = 0; ct < 5; ++ct) {
      const int colbase = 80 * w + 16 * ct;
      if (colbase < NHEAD * DM) {
        const int col = colbase + r;
        #pragma unroll
        for (int j = 0; j < 4; ++j)
          mh_lds[(16 * rt + 4 * q + j) * MH_PITCH + col] = f2b(acc[rt][ct][j]);
      } else {
        const int ltile = 5 * w + ct - 32;
        s16x4 gv;
        gv.x = f2b(fast_sigmoid(acc[rt][ct][0]));
        gv.y = f2b(fast_sigmoid(acc[rt][ct][1]));
        gv.z = f2b(fast_sigmoid(acc[rt][ct][2]));
        gv.w = f2b(fast_sigmoid(acc[rt][ct][3]));
        *reinterpret_cast<s16x4*>(
            gate_lds + ((rt * 8 + ltile) * 64 + lane) * 4) = gv;
      }
    }
  }
  __syncthreads();   // mh_lds + gate_lds complete

  // ---- score phase: wave w = head h = w ----
  const int h = w;
  float wc[8];
  #pragma unroll
  for (int lt = 0; lt < 8; ++lt) wc[lt] = W[(size_t)h * DL + 16 * lt + r];

  bf16x8 a0[4], a1[4];
  #pragma unroll
  for (int rt = 0; rt < 4; ++rt) {
    const short* ap = mh_lds + (16 * rt + r) * MH_PITCH + h * 64 + q * 8;
    a0[rt] = *reinterpret_cast<const bf16x8*>(ap);
    a1[rt] = *reinterpret_cast<const bf16x8*>(ap + 32);
  }

  float sc[4][4];
  #pragma unroll
  for (int rt = 0; rt < 4; ++rt)
    #pragma unroll
    for (int j = 0; j < 4; ++j) sc[rt][j] = 0.f;

  #pragma unroll
  for (int lt = 0; lt < 8; ++lt) {
    bf16x8 b0 = *reinterpret_cast<const bf16x8*>(Vt_f + (size_t)(lt * 2) * 512 + lane * 8);
    bf16x8 b1 = *reinterpret_cast<const bf16x8*>(Vt_f + (size_t)(lt * 2 + 1) * 512 + lane * 8);
    #pragma unroll
    for (int rt = 0; rt < 4; ++rt) {
      f32x4 t = f32x4{0.f, 0.f, 0.f, 0.f};
      t = mfma_bf16(a0[rt], b0, t);
      t = mfma_bf16(a1[rt], b1, t);
      s16x4 ga = *reinterpret_cast<const s16x4*>(
          gate_lds + ((rt * 8 + lt) * 64 + lane) * 4);
      #pragma unroll
      for (int j = 0; j < 4; ++j) {
        float g = b2f((j == 0) ? ga.x : (j == 1) ? ga.y : (j == 2) ? ga.z : ga.w);
        sc[rt][j] += fast_tanh(t[j]) * g * wc[lt];
      }
    }
  }

  // reduce over r-bits; lanes r<4 hold row 16rt+4q+r; e = masked exp(s)
  float epart = 0.f;
  #pragma unroll
  for (int rt = 0; rt < 4; ++rt) {
    #pragma unroll
    for (int j = 0; j < 4; ++j) {
      sc[rt][j] += __shfl_xor(sc[rt][j], 1);
      sc[rt][j] += __shfl_xor(sc[rt][j], 2);
      sc[rt][j] += __shfl_xor(sc[rt][j], 4);
      sc[rt][j] += __shfl_xor(sc[rt][j], 8);
    }
    if (r < 4) {
      const int row = 16 * rt + 4 * q + r;
      float s = (r == 0) ? sc[rt][0] : (r == 1) ? sc[rt][1]
              : (r == 2) ? sc[rt][2] : sc[rt][3];
      float e = (nbase + row < tn) ? __expf(s) : 0.0f;
      e_lds[h * 64 + row] = e;
      epart += e;
    }
  }
  #pragma unroll
  for (int m = 1; m < 64; m <<= 1) epart += __shfl_xor(epart, m);
  if (lane == 0) esum[(size_t)h * NBLK + blk] = epart;

  __syncthreads();   // e_lds complete

  // ---- pool phase: wave h computes part[h][blk][m] over its 64 rows ----
  {
    float P = 0.f;
    const short* mp = mh_lds + h * 64 + lane;
    const float* ep = e_lds + h * 64;
    #pragma unroll 8
    for (int row = 0; row < 64; ++row)
      P += ep[row] * b2f(mp[row * MH_PITCH]);
    part[((size_t)h * NBLK + blk) * 64 + lane] = P;
  }
  if (w == 0) e0[bm0 + lane] = e_lds[lane];
}

// ---------------------------------------------------------------------------
// Kernel 3: finalize. grid 64 = (h,b). Z = sum_c esum; feat = sum_c part / Z;
// h==0 blocks also write out_soft = e0 / Z.
// ---------------------------------------------------------------------------
__global__ __launch_bounds__(256) void finalize_kernel(
    const float* __restrict__ part, const float* __restrict__ esum,
    const float* __restrict__ e0,
    float* __restrict__ out_feat, float* __restrict__ out_soft) {
  const int h = blockIdx.x >> 3, b = blockIdx.x & 7;
  const int tid = threadIdx.x;

  float Z = 0.f;
  #pragma unroll 8
  for (int c = 0; c < 64; ++c) Z += esum[(size_t)h * NBLK + b * 64 + c];
  const float invZ = 1.0f / Z;

  if (tid < 64) {
    float s = 0.f;
    #pragma unroll 8
    for (int c = 0; c < 64; ++c)
      s += part[((size_t)h * NBLK + b * 64 + c) * 64 + tid];
    out_feat[(size_t)b * (NHEAD * DM) + h * DM + tid] = s * invZ;
  }
  if (h == 0) {
    #pragma unroll
    for (int i = 0; i < 16; ++i) {
      const int n = tid + i * 256;
      out_soft[(size_t)b * NINST + n] = e0[(size_t)b * NINST + n] * invZ;
    }
  }
}

// ---------------------------------------------------------------------------
extern "C" void kernel_launch(void* const* d_in, const int* in_sizes, int n_in,
                              void* d_out, int out_size, void* d_ws, size_t ws_size,
                              hipStream_t stream) {
  (void)in_sizes; (void)n_in; (void)out_size; (void)ws_size;
  const float* x      = (const float*)d_in[0];
  const float* WX     = (const float*)d_in[1];
  const float* V      = (const float*)d_in[2];
  const float* W      = (const float*)d_in[3];
  const float* gate_w = (const float*)d_in[4];
  const int* true_num = (const int*)d_in[5];
  float* out = (float*)d_out;

  char* ws = (char*)d_ws;
  short* Wt2  = (short*)ws;  ws += (size_t)(NHEAD * DM + DL) * DIM * 2; //   655,360 B
  short* Vt_f = (short*)ws;  ws += (size_t)DL * DM * 2;                 //    16,384 B
  float* part = (float*)ws;  ws += (size_t)NHEAD * NBLK * 64 * 4;       // 1,048,576 B
  float* esum = (float*)ws;  ws += (size_t)NHEAD * NBLK * 4;            //    16,384 B
  float* e0   = (float*)ws;  ws += (size_t)MTOT * 4;                    //   131,072 B

  prep_weights<<<dim3(145), dim3(256), 0, stream>>>(WX, V, gate_w, Wt2, Vt_f);
  fused_kernel<<<dim3(NBLK), dim3(512), 0, stream>>>(
      x, Wt2, Vt_f, W, true_num, part, esum, e0);
  finalize_kernel<<<dim3(NHEAD * BBAG), dim3(256), 0, stream>>>(
      part, esum, e0, out, out + BBAG * NHEAD * DM);
}